// Round 3
// baseline (655.279 us; speedup 1.0000x reference)
//
#include <hip/hip_runtime.h>
#include <hip/hip_bf16.h>

// FluxJointAttention on MI355X (gfx950), bf16 MFMA pipeline.
// Round 3: QKV GEMM -> 256x256 8-wave phase-split pipelined core (T2+T3+T5+T1),
// both streams merged in one launch. out_gemm stays 128^2; attn unchanged.

typedef __attribute__((ext_vector_type(8))) short s16x8;
typedef __attribute__((ext_vector_type(8))) unsigned short u16x8;
typedef __attribute__((ext_vector_type(4))) float f32x4;
typedef __attribute__((ext_vector_type(16))) float f32x16;

#define DEV static __device__ __forceinline__

#define S_TOT 2560
#define DIMC 3072
#define NQKV 9216

DEV unsigned short f2bf(float f) {
  union { float f; unsigned u; } v; v.f = f;
  return (unsigned short)((v.u + 0x7fffu + ((v.u >> 16) & 1u)) >> 16);
}
DEV float bf2f(unsigned short h) {
  union { unsigned u; float f; } v; v.u = ((unsigned)h) << 16;
  return v.f;
}
DEV void gload16(const void* g, void* l) {
  __builtin_amdgcn_global_load_lds((__attribute__((address_space(1))) void*)g,
                                   (__attribute__((address_space(3))) void*)l,
                                   16, 0, 0);
}
DEV float exp2_fast(float x) {
#if __has_builtin(__builtin_amdgcn_exp2f)
  return __builtin_amdgcn_exp2f(x);
#else
  return __expf(x * 0.69314718056f);
#endif
}
template <int CTRL>
DEV float dppf(float x) {
  return __int_as_float(__builtin_amdgcn_update_dpp(0, __float_as_int(x), CTRL, 0xf, 0xf, true));
}
DEV float rowmax16(float x) {
  x = fmaxf(x, dppf<0xB1>(x));
  x = fmaxf(x, dppf<0x4E>(x));
  x = fmaxf(x, dppf<0x141>(x));
  x = fmaxf(x, dppf<0x140>(x));
  return x;
}
DEV float rowsum16(float x) {
  x += dppf<0xB1>(x);
  x += dppf<0x4E>(x);
  x += dppf<0x141>(x);
  x += dppf<0x140>(x);
  return x;
}

// ---------------- conversion kernels ----------------

__global__ __launch_bounds__(256) void cvt_bf16_k(const float* __restrict__ in,
                                                  unsigned short* __restrict__ out,
                                                  int n8) {
  int i = blockIdx.x * 256 + threadIdx.x;
  if (i >= n8) return;
  const float4* p = (const float4*)(in + (size_t)i * 8);
  float4 a = p[0], b = p[1];
  u16x8 u;
  u[0] = f2bf(a.x); u[1] = f2bf(a.y); u[2] = f2bf(a.z); u[3] = f2bf(a.w);
  u[4] = f2bf(b.x); u[5] = f2bf(b.y); u[6] = f2bf(b.z); u[7] = f2bf(b.w);
  *(u16x8*)(out + (size_t)i * 8) = u;
}

__global__ __launch_bounds__(256) void transpose_cvt(const float* __restrict__ W,
                                                     unsigned short* __restrict__ WT,
                                                     int K, int N) {
  __shared__ float tile[64][65];
  const int t = threadIdx.x;
  const int n0 = blockIdx.x * 64, k0 = blockIdx.y * 64;
#pragma unroll
  for (int rep = 0; rep < 4; ++rep) {
    int idx = rep * 256 + t;
    int r = idx >> 4, c4 = (idx & 15) * 4;
    float4 v = *(const float4*)&W[(size_t)(k0 + r) * N + n0 + c4];
    tile[r][c4] = v.x; tile[r][c4 + 1] = v.y; tile[r][c4 + 2] = v.z; tile[r][c4 + 3] = v.w;
  }
  __syncthreads();
#pragma unroll
  for (int rep = 0; rep < 2; ++rep) {
    int idx = rep * 256 + t;
    int j = idx >> 3, i0 = (idx & 7) * 8;
    u16x8 u;
#pragma unroll
    for (int i = 0; i < 8; i++) u[i] = f2bf(tile[i0 + i][j]);
    *(u16x8*)&WT[(size_t)(n0 + j) * K + k0 + i0] = u;
  }
}

// ======== 256x256 8-wave pipelined QKV GEMM + RMS/RoPE/V-transpose ========
// LDS: 2 buffers x (A 256x64 + B 256x64) bf16, rows 128B XOR-swizzled
// ((row&7)<<4). Stage writes linear (gload_lds), source pre-swizzled.
// Per K-tile: 4 quadrant phases; each stages 1/4 of next tile into buf^1.

DEV int cta(int r, int cb) {  // epilogue C-tile: 512B rows, XOR bits 5-8 by row&15
  return (r << 9) + (cb ^ ((r & 15) << 5));
}

DEV void stage_half(const char* panel128, char* dst16k, int kt, int tid) {
  // panel128: matrix panel pre-offset to this half's row 0 (row stride 6144B)
  int slot = tid & 7;
  int r = tid >> 3;  // 0..63
#pragma unroll
  for (int l = 0; l < 2; ++l) {
    int row = r + l * 64;
    gload16(panel128 + (size_t)row * 6144 + kt * 128 + ((slot * 16) ^ ((row & 7) << 4)),
            dst16k + (l * 512 + tid) * 16);
  }
}

__global__ __launch_bounds__(512, 2) void qkv256(
    const unsigned short* __restrict__ A0, const unsigned short* __restrict__ A1,
    const unsigned short* __restrict__ W0, const unsigned short* __restrict__ W1,
    const float* __restrict__ b0, const float* __restrict__ b1,
    const float* __restrict__ wqa, const float* __restrict__ wka,
    const float* __restrict__ wqb, const float* __restrict__ wkb,
    const float* __restrict__ freqs,
    unsigned short* __restrict__ Qb, unsigned short* __restrict__ Kb,
    unsigned short* __restrict__ Vt, int nt0, int ncols) {
  __shared__ __align__(128) char smem[131072];
  const int tid = threadIdx.x;
  const int w = tid >> 6, lane = tid & 63;
  const int wr = w >> 2, wc = w & 3;
  const int lh = lane >> 4, ll = lane & 15;

  // bijective XCD swizzle (gridDim.x % 8 == 0)
  const int chunk = gridDim.x >> 3;
  const int nid = ((int)blockIdx.x & 7) * chunk + ((int)blockIdx.x >> 3);
  const int strm = (nid >= nt0) ? 1 : 0;
  const int t = strm ? nid - nt0 : nid;
  const int m0 = (t / ncols) * 256, n0 = (t % ncols) * 256;
  const char* ApC = (const char*)((strm ? A1 : A0) + (size_t)m0 * DIMC);
  const char* BpC = (const char*)((strm ? W1 : W0) + (size_t)n0 * DIMC);
  const float* biasp = (strm ? b1 : b0) + n0;
  const int s_off = strm ? 0 : 512;

  f32x4 acc[8][4] = {};

  // prologue: stage tile 0 into buf0
  stage_half(ApC, smem, 0, tid);
  stage_half(ApC + 128 * 6144, smem + 16384, 0, tid);
  stage_half(BpC, smem + 32768, 0, tid);
  stage_half(BpC + 128 * 6144, smem + 49152, 0, tid);
  __syncthreads();

  int cur = 0;
  for (int kt = 0; kt < 48; ++kt) {
    const char* Ab = smem + cur * 65536;
    const char* Bb = smem + cur * 65536 + 32768;
    char* An = smem + (cur ^ 1) * 65536;
    const bool pre = (kt + 1 < 48);
    s16x8 a[4][2], b[2][2];
#pragma unroll
    for (int q = 0; q < 4; ++q) {
      const int mh = q >> 1, nh = q & 1;
      if (nh == 0) {
#pragma unroll
        for (int f = 0; f < 4; ++f) {
          int ar = wr * 128 + mh * 64 + f * 16 + ll;
#pragma unroll
          for (int ks = 0; ks < 2; ++ks)
            a[f][ks] = *(const s16x8*)(Ab + ar * 128 + ((ks * 64 + lh * 16) ^ ((ar & 7) << 4)));
        }
      }
#pragma unroll
      for (int g = 0; g < 2; ++g) {
        int br = wc * 64 + nh * 32 + g * 16 + ll;
#pragma unroll
        for (int ks = 0; ks < 2; ++ks)
          b[g][ks] = *(const s16x8*)(Bb + br * 128 + ((ks * 64 + lh * 16) ^ ((br & 7) << 4)));
      }
      if (pre) {
        const char* pan = (q < 2) ? ApC : BpC;
        stage_half(pan + (q & 1) * (128 * 6144),
                   An + (q >> 1) * 32768 + (q & 1) * 16384, kt + 1, tid);
      }
      __builtin_amdgcn_s_barrier();
      __builtin_amdgcn_s_setprio(1);
#pragma unroll
      for (int f = 0; f < 4; ++f)
#pragma unroll
        for (int g = 0; g < 2; ++g)
#pragma unroll
          for (int ks = 0; ks < 2; ++ks)
            acc[mh * 4 + f][nh * 2 + g] = __builtin_amdgcn_mfma_f32_16x16x32_bf16(
                a[f][ks], b[g][ks], acc[mh * 4 + f][nh * 2 + g], 0, 0, 0);
      __builtin_amdgcn_s_setprio(0);
      __builtin_amdgcn_s_barrier();
    }
    __syncthreads();  // boundary: drains vm (prefetch) + lgkm, swaps buffers
    cur ^= 1;
  }

  // ---- epilogue: acc + bias -> swizzled bf16 ctile (reuse smem) ----
#pragma unroll
  for (int fn = 0; fn < 4; ++fn) {
    int c = wc * 64 + fn * 16 + ll;
    float bv = biasp[c];
#pragma unroll
    for (int fm = 0; fm < 8; ++fm)
#pragma unroll
      for (int j = 0; j < 4; ++j) {
        int r = wr * 128 + fm * 16 + lh * 4 + j;
        *(unsigned short*)(smem + cta(r, 2 * c)) = f2bf(acc[fm][fn][j] + bv);
      }
  }
  __syncthreads();

  const int qkvi = n0 / DIMC;
  const int h0 = (n0 % DIMC) / 128;

  if (qkvi < 2) {
    // RMS over each head's 128 cols + RoPE; 512 threads = 256 rows x 2 heads
    const float* wn = (qkvi == 0) ? (strm ? wqb : wqa) : (strm ? wkb : wka);
    unsigned short* Ob = (qkvi == 0) ? Qb : Kb;
    const int row = tid >> 1, hc = tid & 1;
    const int sg = s_off + m0 + row;
    const int head = h0 + hc;
    u16x8 xv[16];
    float ss = 0.f;
#pragma unroll
    for (int k = 0; k < 16; ++k) {
      xv[k] = *(const u16x8*)(smem + cta(row, hc * 256 + k * 16));
#pragma unroll
      for (int i = 0; i < 8; ++i) { float v = bf2f(xv[k][i]); ss += v * v; }
    }
    const float rn = rsqrtf(ss * (1.f / 128.f) + 1e-6f);
    const float* fr = freqs + (size_t)sg * 256;
    size_t ob = ((size_t)head * S_TOT + sg) * 128;
#pragma unroll
    for (int k = 0; k < 16; ++k) {
      u16x8 u;
#pragma unroll
      for (int pp = 0; pp < 4; ++pp) {
        int d0 = k * 8 + pp * 2;
        float y0 = bf2f(xv[k][pp * 2]) * rn * wn[d0];
        float y1 = bf2f(xv[k][pp * 2 + 1]) * rn * wn[d0 + 1];
        int p = d0 >> 1;
        float f0 = fr[p * 4], f1 = fr[p * 4 + 1], f2v = fr[p * 4 + 2], f3 = fr[p * 4 + 3];
        u[pp * 2] = f2bf(f0 * y0 + f1 * y1);
        u[pp * 2 + 1] = f2bf(f2v * y0 + f3 * y1);
      }
      *(u16x8*)&Ob[ob + k * 8] = u;
    }
  } else {
    // V: transposed store Vt[h][d][s]
    const int hv = tid >> 8, d = (tid & 255) >> 1, sh = tid & 1;
    const int head = h0 + hv;
    const int c = hv * 128 + d;
    size_t obase = ((size_t)head * 128 + d) * S_TOT + s_off + m0 + sh * 128;
#pragma unroll
    for (int v8 = 0; v8 < 16; ++v8) {
      u16x8 u;
#pragma unroll
      for (int i = 0; i < 8; ++i)
        u[i] = *(const unsigned short*)(smem + cta(sh * 128 + v8 * 8 + i, 2 * c));
      *(u16x8*)&Vt[obase + v8 * 8] = u;
    }
  }
}

// ---------------- 128x128 GEMM core (out projection) ----------------

struct StageSmem {
  unsigned short A[128 * 64];
  unsigned short B[128 * 64];
};

DEV void gemm_core(const unsigned short* __restrict__ Ap,
                   const unsigned short* __restrict__ Bp,
                   StageSmem* sm, int tid, f32x4 (&acc)[4][4]) {
  const int wave = tid >> 6, lane = tid & 63;
  const int wr = wave >> 1, wc = wave & 1;
  const int lh = lane >> 4, ll = lane & 15;
  const int row_s = tid >> 3;
  const int kbp = (tid & 7) * 16;

  for (int kt = 0; kt < 48; ++kt) {
    __syncthreads();
#pragma unroll
    for (int st = 0; st < 4; ++st) {
      int row = st * 32 + row_s;
      int kb = kbp ^ ((row & 7) << 4);
      gload16((const char*)(Ap + (size_t)row * DIMC) + kt * 128 + kb,
              (char*)sm->A + st * 4096 + tid * 16);
      gload16((const char*)(Bp + (size_t)row * DIMC) + kt * 128 + kb,
              (char*)sm->B + st * 4096 + tid * 16);
    }
    __syncthreads();
#pragma unroll
    for (int ks = 0; ks < 2; ++ks) {
      s16x8 a[4], b[4];
#pragma unroll
      for (int f = 0; f < 4; ++f) {
        int ar = wr * 64 + f * 16 + ll;
        a[f] = *(const s16x8*)((const char*)sm->A + ar * 128 +
                               ((ks * 64 + lh * 16) ^ ((ar & 7) << 4)));
        int br = wc * 64 + f * 16 + ll;
        b[f] = *(const s16x8*)((const char*)sm->B + br * 128 +
                               ((ks * 64 + lh * 16) ^ ((br & 7) << 4)));
      }
#pragma unroll
      for (int i = 0; i < 4; i++)
#pragma unroll
        for (int j = 0; j < 4; j++)
          acc[i][j] = __builtin_amdgcn_mfma_f32_16x16x32_bf16(a[i], b[j], acc[i][j], 0, 0, 0);
    }
  }
  __syncthreads();
}

__global__ __launch_bounds__(256, 2) void out_gemm(
    const unsigned short* __restrict__ A, const unsigned short* __restrict__ WT,
    const float* __restrict__ bias, float* __restrict__ C) {
  __shared__ StageSmem sm;
  const int tid = threadIdx.x;
  const int m0 = blockIdx.y * 128, n0 = blockIdx.x * 128;
  f32x4 acc[4][4] = {};
  gemm_core(A + (size_t)m0 * DIMC, WT + (size_t)n0 * DIMC, &sm, tid, acc);
  const int wave = tid >> 6, lane = tid & 63;
  const int wr = wave >> 1, wc = wave & 1, lh = lane >> 4, ll = lane & 15;
#pragma unroll
  for (int fn = 0; fn < 4; ++fn) {
    int c = n0 + wc * 64 + fn * 16 + ll;
    float bv = bias[c];
#pragma unroll
    for (int fm = 0; fm < 4; ++fm)
#pragma unroll
      for (int j = 0; j < 4; j++) {
        int r = m0 + wr * 64 + fm * 16 + lh * 4 + j;
        C[(size_t)r * DIMC + c] = acc[fm][fn][j] + bv;
      }
  }
}

// ---------------- flash attention (unchanged from round 2) ----------------

__global__ __launch_bounds__(256, 2) void attn_k(
    const unsigned short* __restrict__ Qb, const unsigned short* __restrict__ Kb,
    const unsigned short* __restrict__ Vt, unsigned short* __restrict__ AO) {
  __shared__ alignas(128) unsigned short Ks[2][64 * 128];
  __shared__ alignas(128) unsigned short Vs[128 * 64];
  __shared__ alignas(128) unsigned short Ps[4][32 * 72];
  __shared__ float tabA[4][32];
  __shared__ float tabL[4][32];

  const int tid = threadIdx.x, w = tid >> 6, lane = tid & 63;
  const int lh = lane >> 4, ll16 = lane & 15;
  const int ll31 = lane & 31, hi = lane >> 5;
  const int wgid = blockIdx.x;
  const int nid = (wgid & 7) * 60 + (wgid >> 3);
  const int h = nid / 20, qt = nid % 20;
  const float C = 0.12751744f;  // (1/sqrt(128)) * log2(e)

  s16x8 qf[2][4];
#pragma unroll
  for (int rb = 0; rb < 2; rb++) {
    size_t qbase = ((size_t)h * S_TOT + qt * 128 + w * 32 + rb * 16 + ll16) * 128;
#pragma unroll
    for (int ks = 0; ks < 4; ks++) qf[rb][ks] = *(const s16x8*)&Qb[qbase + ks * 32 + lh * 8];
  }

  float m2[2][4], l_r[2][4];
  f32x16 o[4] = {};
#pragma unroll
  for (int rb = 0; rb < 2; rb++)
#pragma unroll
    for (int j = 0; j < 4; j++) { m2[rb][j] = -1e30f; l_r[rb][j] = 0.f; }

  const unsigned short* Kh = Kb + (size_t)h * S_TOT * 128;
  const unsigned short* Vh = Vt + (size_t)h * 128 * S_TOT;
  unsigned short* Pw = &Ps[w][0];

  {
#pragma unroll
    for (int st = 0; st < 4; ++st) {
      int row = st * 16 + (tid >> 4);
      int col = ((tid & 15) * 16) ^ ((row & 7) << 4);
      gload16((const char*)(Kh + (size_t)row * 128) + col,
              (char*)&Ks[0][0] + st * 4096 + tid * 16);
    }
  }

  int cur = 0;
  for (int kt = 0; kt < 40; ++kt) {
    __syncthreads();
    {
      const int k0 = kt * 64;
#pragma unroll
      for (int st = 0; st < 4; ++st) {
        int row = st * 32 + (tid >> 3);
        int col = ((tid & 7) * 16) ^ ((row & 7) << 4);
        gload16((const char*)(Vh + (size_t)row * S_TOT + k0) + col,
                (char*)Vs + st * 4096 + tid * 16);
      }
    }
    if (kt + 1 < 40) {
      const unsigned short* Kn = Kh + (size_t)(kt + 1) * 64 * 128;
#pragma unroll
      for (int st = 0; st < 4; ++st) {
        int row = st * 16 + (tid >> 4);
        int col = ((tid & 15) * 16) ^ ((row & 7) << 4);
        gload16((const char*)(Kn + (size_t)row * 128) + col,
                (char*)&Ks[cur ^ 1][0] + st * 4096 + tid * 16);
      }
    }

    const char* Kc = (const char*)&Ks[cur][0];
    f32x4 sc[2][4] = {};
#pragma unroll
    for (int kb = 0; kb < 4; kb++) {
      int krow = kb * 16 + ll16;
      const char* kr = Kc + krow * 256;
      int swz = (krow & 7) << 4;
#pragma unroll
      for (int ks = 0; ks < 4; ks++) {
        s16x8 bf = *(const s16x8*)(kr + ((ks * 64 + lh * 16) ^ swz));
        sc[0][kb] = __builtin_amdgcn_mfma_f32_16x16x32_bf16(qf[0][ks], bf, sc[0][kb], 0, 0, 0);
        sc[1][kb] = __builtin_amdgcn_mfma_f32_16x16x32_bf16(qf[1][ks], bf, sc[1][kb], 0, 0, 0);
      }
    }

    float pmax[2][4];
#pragma unroll
    for (int rb = 0; rb < 2; rb++)
#pragma unroll
      for (int j = 0; j < 4; j++) {
        float v = fmaxf(fmaxf(sc[rb][0][j], sc[rb][1][j]), fmaxf(sc[rb][2][j], sc[rb][3][j]));
        pmax[rb][j] = rowmax16(v) * C;
      }
    bool need = false;
#pragma unroll
    for (int rb = 0; rb < 2; rb++)
#pragma unroll
      for (int j = 0; j < 4; j++) need |= (pmax[rb][j] > m2[rb][j] + 8.0f);
    if (__any(need)) {
#pragma unroll
      for (int rb = 0; rb < 2; rb++)
#pragma unroll
        for (int j = 0; j < 4; j++) {
          float mn = fmaxf(m2[rb][j], pmax[rb][j]);
          float al = exp2_fast(m2[rb][j] - mn);
          m2[rb][j] = mn;
          l_r[rb][j] *= al;
          if (ll16 == 0) tabA[w][rb * 16 + lh * 4 + j] = al;
        }
#pragma unroll
      for (int reg = 0; reg < 16; reg++) {
        int cr = (reg & 3) + 8 * (reg >> 2) + 4 * hi;
        float alv = tabA[w][cr];
        o[0][reg] *= alv; o[1][reg] *= alv; o[2][reg] *= alv; o[3][reg] *= alv;
      }
    }
#pragma unroll
    for (int rb = 0; rb < 2; rb++) {
      float ps0 = 0.f, ps1 = 0.f, ps2 = 0.f, ps3 = 0.f;
#pragma unroll
      for (int kb = 0; kb < 4; kb++) {
        float p0 = exp2_fast(sc[rb][kb][0] * C - m2[rb][0]);
        float p1 = exp2_fast(sc[rb][kb][1] * C - m2[rb][1]);
        float p2 = exp2_fast(sc[rb][kb][2] * C - m2[rb][2]);
        float p3 = exp2_fast(sc[rb][kb][3] * C - m2[rb][3]);
        ps0 += p0; ps1 += p1; ps2 += p2; ps3 += p3;
        int rbase = (rb * 16 + lh * 4);
        Pw[(rbase + 0) * 72 + kb * 16 + ll16] = f2bf(p0);
        Pw[(rbase + 1) * 72 + kb * 16 + ll16] = f2bf(p1);
        Pw[(rbase + 2) * 72 + kb * 16 + ll16] = f2bf(p2);
        Pw[(rbase + 3) * 72 + kb * 16 + ll16] = f2bf(p3);
      }
      l_r[rb][0] += rowsum16(ps0);
      l_r[rb][1] += rowsum16(ps1);
      l_r[rb][2] += rowsum16(ps2);
      l_r[rb][3] += rowsum16(ps3);
    }

    __syncthreads();

#pragma unroll
    for (int kstep = 0; kstep < 4; kstep++) {
      s16x8 pa = *(const s16x8*)((const char*)Pw + ll31 * 144 + kstep * 32 + hi * 16);
#pragma unroll
      for (int dblk = 0; dblk < 4; dblk++) {
        int vrow = dblk * 32 + ll31;
        s16x8 vb = *(const s16x8*)((const char*)Vs + vrow * 128 +
                                   ((kstep * 32 + hi * 16) ^ ((vrow & 7) << 4)));
        o[dblk] = __builtin_amdgcn_mfma_f32_32x32x16_bf16(pa, vb, o[dblk], 0, 0, 0);
      }
    }
    cur ^= 1;
  }

  if (ll16 == 0) {
#pragma unroll
    for (int rb = 0; rb < 2; rb++)
#pragma unroll
      for (int j = 0; j < 4; j++) tabL[w][rb * 16 + lh * 4 + j] = l_r[rb][j];
  }
#pragma unroll
  for (int reg = 0; reg < 16; reg++) {
    int cr = (reg & 3) + 8 * (reg >> 2) + 4 * hi;
    float inv = 1.0f / tabL[w][cr];
    int srow = qt * 128 + w * 32 + cr;
    size_t base = (size_t)srow * DIMC + h * 128;
#pragma unroll
    for (int dblk = 0; dblk < 4; dblk++)
      AO[base + dblk * 32 + ll31] = f2bf(o[dblk][reg] * inv);
  }
}

// ---------------- launcher ----------------

extern "C" void kernel_launch(void* const* d_in, const int* in_sizes, int n_in,
                              void* d_out, int out_size, void* d_ws, size_t ws_size,
                              hipStream_t stream) {
  (void)in_sizes; (void)n_in; (void)out_size; (void)ws_size;
  const float* Xa = (const float*)d_in[0];
  const float* Xb = (const float*)d_in[1];
  const float* freqs = (const float*)d_in[2];
  const float* Wqkv_a = (const float*)d_in[3];
  const float* bqkv_a = (const float*)d_in[4];
  const float* Wqkv_b = (const float*)d_in[5];
  const float* bqkv_b = (const float*)d_in[6];
  const float* wq_a = (const float*)d_in[7];
  const float* wk_a = (const float*)d_in[8];
  const float* wq_b = (const float*)d_in[9];
  const float* wk_b = (const float*)d_in[10];
  const float* Wout_a = (const float*)d_in[11];
  const float* bout_a = (const float*)d_in[12];
  const float* Wout_b = (const float*)d_in[13];
  const float* bout_b = (const float*)d_in[14];
  float* out = (float*)d_out;

  char* ws = (char*)d_ws;
  unsigned short* WTa  = (unsigned short*)ws; ws += (size_t)NQKV * DIMC * 2;
  unsigned short* WTb  = (unsigned short*)ws; ws += (size_t)NQKV * DIMC * 2;
  unsigned short* WoTa = (unsigned short*)ws; ws += (size_t)DIMC * DIMC * 2;
  unsigned short* WoTb = (unsigned short*)ws; ws += (size_t)DIMC * DIMC * 2;
  unsigned short* Xa16 = (unsigned short*)ws; ws += (size_t)2048 * DIMC * 2;
  unsigned short* Xb16 = (unsigned short*)ws; ws += (size_t)512 * DIMC * 2;
  unsigned short* Qb   = (unsigned short*)ws; ws += (size_t)24 * S_TOT * 128 * 2;
  unsigned short* Kbf  = (unsigned short*)ws; ws += (size_t)24 * S_TOT * 128 * 2;
  unsigned short* Vt   = (unsigned short*)ws; ws += (size_t)24 * S_TOT * 128 * 2;
  unsigned short* AO   = (unsigned short*)ws; ws += (size_t)S_TOT * DIMC * 2;

  cvt_bf16_k<<<dim3(2048 * DIMC / 8 / 256), dim3(256), 0, stream>>>(Xa, Xa16, 2048 * DIMC / 8);
  cvt_bf16_k<<<dim3(512 * DIMC / 8 / 256), dim3(256), 0, stream>>>(Xb, Xb16, 512 * DIMC / 8);
  transpose_cvt<<<dim3(NQKV / 64, DIMC / 64), dim3(256), 0, stream>>>(Wqkv_a, WTa, DIMC, NQKV);
  transpose_cvt<<<dim3(NQKV / 64, DIMC / 64), dim3(256), 0, stream>>>(Wqkv_b, WTb, DIMC, NQKV);
  transpose_cvt<<<dim3(DIMC / 64, DIMC / 64), dim3(256), 0, stream>>>(Wout_a, WoTa, DIMC, DIMC);
  transpose_cvt<<<dim3(DIMC / 64, DIMC / 64), dim3(256), 0, stream>>>(Wout_b, WoTb, DIMC, DIMC);

  // merged QKV: stream a = 8x36 tiles, stream b = 2x36 tiles -> 360 blocks
  qkv256<<<dim3(360), dim3(512), 0, stream>>>(Xa16, Xb16, WTa, WTb, bqkv_a, bqkv_b,
                                              wq_a, wk_a, wq_b, wk_b, freqs,
                                              Qb, Kbf, Vt, 288, 36);

  attn_k<<<dim3(480), dim3(256), 0, stream>>>(Qb, Kbf, Vt, AO);

  out_gemm<<<dim3(24, 16), dim3(256), 0, stream>>>(AO + (size_t)512 * DIMC, WoTa, bout_a, out);
  out_gemm<<<dim3(24, 4), dim3(256), 0, stream>>>(AO, WoTb, bout_b, out + (size_t)2048 * DIMC);
}

// Round 4
// 638.903 us; speedup vs baseline: 1.0256x; 1.0256x over previous
//
#include <hip/hip_runtime.h>
#include <hip/hip_bf16.h>

// FluxJointAttention on MI355X (gfx950), bf16 MFMA pipeline.
// Round 4: qkv256 stages ALL 4 half-tiles of t+1 at phase 0 (3 phases of MFMA
// cover before the boundary drain). gemm_core (out-proj) -> 2-buffer prefetch
// issued before compute. attn unchanged.

typedef __attribute__((ext_vector_type(8))) short s16x8;
typedef __attribute__((ext_vector_type(8))) unsigned short u16x8;
typedef __attribute__((ext_vector_type(4))) float f32x4;
typedef __attribute__((ext_vector_type(16))) float f32x16;

#define DEV static __device__ __forceinline__

#define S_TOT 2560
#define DIMC 3072
#define NQKV 9216

DEV unsigned short f2bf(float f) {
  union { float f; unsigned u; } v; v.f = f;
  return (unsigned short)((v.u + 0x7fffu + ((v.u >> 16) & 1u)) >> 16);
}
DEV float bf2f(unsigned short h) {
  union { unsigned u; float f; } v; v.u = ((unsigned)h) << 16;
  return v.f;
}
DEV void gload16(const void* g, void* l) {
  __builtin_amdgcn_global_load_lds((__attribute__((address_space(1))) void*)g,
                                   (__attribute__((address_space(3))) void*)l,
                                   16, 0, 0);
}
DEV float exp2_fast(float x) {
#if __has_builtin(__builtin_amdgcn_exp2f)
  return __builtin_amdgcn_exp2f(x);
#else
  return __expf(x * 0.69314718056f);
#endif
}
template <int CTRL>
DEV float dppf(float x) {
  return __int_as_float(__builtin_amdgcn_update_dpp(0, __float_as_int(x), CTRL, 0xf, 0xf, true));
}
DEV float rowmax16(float x) {
  x = fmaxf(x, dppf<0xB1>(x));
  x = fmaxf(x, dppf<0x4E>(x));
  x = fmaxf(x, dppf<0x141>(x));
  x = fmaxf(x, dppf<0x140>(x));
  return x;
}
DEV float rowsum16(float x) {
  x += dppf<0xB1>(x);
  x += dppf<0x4E>(x);
  x += dppf<0x141>(x);
  x += dppf<0x140>(x);
  return x;
}

// ---------------- conversion kernels ----------------

__global__ __launch_bounds__(256) void cvt_bf16_k(const float* __restrict__ in,
                                                  unsigned short* __restrict__ out,
                                                  int n8) {
  int i = blockIdx.x * 256 + threadIdx.x;
  if (i >= n8) return;
  const float4* p = (const float4*)(in + (size_t)i * 8);
  float4 a = p[0], b = p[1];
  u16x8 u;
  u[0] = f2bf(a.x); u[1] = f2bf(a.y); u[2] = f2bf(a.z); u[3] = f2bf(a.w);
  u[4] = f2bf(b.x); u[5] = f2bf(b.y); u[6] = f2bf(b.z); u[7] = f2bf(b.w);
  *(u16x8*)(out + (size_t)i * 8) = u;
}

__global__ __launch_bounds__(256) void transpose_cvt(const float* __restrict__ W,
                                                     unsigned short* __restrict__ WT,
                                                     int K, int N) {
  __shared__ float tile[64][65];
  const int t = threadIdx.x;
  const int n0 = blockIdx.x * 64, k0 = blockIdx.y * 64;
#pragma unroll
  for (int rep = 0; rep < 4; ++rep) {
    int idx = rep * 256 + t;
    int r = idx >> 4, c4 = (idx & 15) * 4;
    float4 v = *(const float4*)&W[(size_t)(k0 + r) * N + n0 + c4];
    tile[r][c4] = v.x; tile[r][c4 + 1] = v.y; tile[r][c4 + 2] = v.z; tile[r][c4 + 3] = v.w;
  }
  __syncthreads();
#pragma unroll
  for (int rep = 0; rep < 2; ++rep) {
    int idx = rep * 256 + t;
    int j = idx >> 3, i0 = (idx & 7) * 8;
    u16x8 u;
#pragma unroll
    for (int i = 0; i < 8; i++) u[i] = f2bf(tile[i0 + i][j]);
    *(u16x8*)&WT[(size_t)(n0 + j) * K + k0 + i0] = u;
  }
}

// ======== 256x256 8-wave pipelined QKV GEMM + RMS/RoPE/V-transpose ========
// LDS: 2 buffers x (A 256x64 + B 256x64) bf16, rows 128B XOR-swizzled
// ((row&7)<<4). Stage writes linear (gload_lds), source pre-swizzled.
// All 4 half-tiles of tile t+1 staged at phase 0 of tile t -> ~3 phases of
// MFMA cover before the boundary __syncthreads drains them.

DEV int cta(int r, int cb) {  // epilogue C-tile: 512B rows, XOR bits 5-8 by row&15
  return (r << 9) + (cb ^ ((r & 15) << 5));
}

DEV void stage_half(const char* panel128, char* dst16k, int kt, int tid) {
  int slot = tid & 7;
  int r = tid >> 3;  // 0..63
#pragma unroll
  for (int l = 0; l < 2; ++l) {
    int row = r + l * 64;
    gload16(panel128 + (size_t)row * 6144 + kt * 128 + ((slot * 16) ^ ((row & 7) << 4)),
            dst16k + (l * 512 + tid) * 16);
  }
}

__global__ __launch_bounds__(512, 2) void qkv256(
    const unsigned short* __restrict__ A0, const unsigned short* __restrict__ A1,
    const unsigned short* __restrict__ W0, const unsigned short* __restrict__ W1,
    const float* __restrict__ b0, const float* __restrict__ b1,
    const float* __restrict__ wqa, const float* __restrict__ wka,
    const float* __restrict__ wqb, const float* __restrict__ wkb,
    const float* __restrict__ freqs,
    unsigned short* __restrict__ Qb, unsigned short* __restrict__ Kb,
    unsigned short* __restrict__ Vt, int nt0, int ncols) {
  __shared__ __align__(128) char smem[131072];
  const int tid = threadIdx.x;
  const int w = tid >> 6, lane = tid & 63;
  const int wr = w >> 2, wc = w & 3;
  const int lh = lane >> 4, ll = lane & 15;

  const int chunk = gridDim.x >> 3;
  const int nid = ((int)blockIdx.x & 7) * chunk + ((int)blockIdx.x >> 3);
  const int strm = (nid >= nt0) ? 1 : 0;
  const int t = strm ? nid - nt0 : nid;
  const int m0 = (t / ncols) * 256, n0 = (t % ncols) * 256;
  const char* ApC = (const char*)((strm ? A1 : A0) + (size_t)m0 * DIMC);
  const char* BpC = (const char*)((strm ? W1 : W0) + (size_t)n0 * DIMC);
  const float* biasp = (strm ? b1 : b0) + n0;
  const int s_off = strm ? 0 : 512;

  f32x4 acc[8][4] = {};

  // prologue: stage tile 0 into buf0
  stage_half(ApC, smem, 0, tid);
  stage_half(ApC + 128 * 6144, smem + 16384, 0, tid);
  stage_half(BpC, smem + 32768, 0, tid);
  stage_half(BpC + 128 * 6144, smem + 49152, 0, tid);
  __syncthreads();

  int cur = 0;
  for (int kt = 0; kt < 48; ++kt) {
    const char* Ab = smem + cur * 65536;
    const char* Bb = smem + cur * 65536 + 32768;
    char* An = smem + (cur ^ 1) * 65536;
    const bool pre = (kt + 1 < 48);
    s16x8 a[4][2], b[2][2];
#pragma unroll
    for (int q = 0; q < 4; ++q) {
      const int mh = q >> 1, nh = q & 1;
      if (nh == 0) {
#pragma unroll
        for (int f = 0; f < 4; ++f) {
          int ar = wr * 128 + mh * 64 + f * 16 + ll;
#pragma unroll
          for (int ks = 0; ks < 2; ++ks)
            a[f][ks] = *(const s16x8*)(Ab + ar * 128 + ((ks * 64 + lh * 16) ^ ((ar & 7) << 4)));
        }
      }
#pragma unroll
      for (int g = 0; g < 2; ++g) {
        int br = wc * 64 + nh * 32 + g * 16 + ll;
#pragma unroll
        for (int ks = 0; ks < 2; ++ks)
          b[g][ks] = *(const s16x8*)(Bb + br * 128 + ((ks * 64 + lh * 16) ^ ((br & 7) << 4)));
      }
      if (q == 0 && pre) {
        // stage ALL of tile kt+1 now: 3 phases of MFMA cover the latency
        stage_half(ApC, An, kt + 1, tid);
        stage_half(ApC + 128 * 6144, An + 16384, kt + 1, tid);
        stage_half(BpC, An + 32768, kt + 1, tid);
        stage_half(BpC + 128 * 6144, An + 49152, kt + 1, tid);
      }
      __builtin_amdgcn_s_barrier();
      __builtin_amdgcn_s_setprio(1);
#pragma unroll
      for (int f = 0; f < 4; ++f)
#pragma unroll
        for (int g = 0; g < 2; ++g)
#pragma unroll
          for (int ks = 0; ks < 2; ++ks)
            acc[mh * 4 + f][nh * 2 + g] = __builtin_amdgcn_mfma_f32_16x16x32_bf16(
                a[f][ks], b[g][ks], acc[mh * 4 + f][nh * 2 + g], 0, 0, 0);
      __builtin_amdgcn_s_setprio(0);
      __builtin_amdgcn_s_barrier();
    }
    __syncthreads();  // boundary drain: prefetch loads are ~3 phases old
    cur ^= 1;
  }

  // ---- epilogue: acc + bias -> swizzled bf16 ctile (reuse smem) ----
#pragma unroll
  for (int fn = 0; fn < 4; ++fn) {
    int c = wc * 64 + fn * 16 + ll;
    float bv = biasp[c];
#pragma unroll
    for (int fm = 0; fm < 8; ++fm)
#pragma unroll
      for (int j = 0; j < 4; ++j) {
        int r = wr * 128 + fm * 16 + lh * 4 + j;
        *(unsigned short*)(smem + cta(r, 2 * c)) = f2bf(acc[fm][fn][j] + bv);
      }
  }
  __syncthreads();

  const int qkvi = n0 / DIMC;
  const int h0 = (n0 % DIMC) / 128;

  if (qkvi < 2) {
    const float* wn = (qkvi == 0) ? (strm ? wqb : wqa) : (strm ? wkb : wka);
    unsigned short* Ob = (qkvi == 0) ? Qb : Kb;
    const int row = tid >> 1, hc = tid & 1;
    const int sg = s_off + m0 + row;
    const int head = h0 + hc;
    u16x8 xv[16];
    float ss = 0.f;
#pragma unroll
    for (int k = 0; k < 16; ++k) {
      xv[k] = *(const u16x8*)(smem + cta(row, hc * 256 + k * 16));
#pragma unroll
      for (int i = 0; i < 8; ++i) { float v = bf2f(xv[k][i]); ss += v * v; }
    }
    const float rn = rsqrtf(ss * (1.f / 128.f) + 1e-6f);
    const float* fr = freqs + (size_t)sg * 256;
    size_t ob = ((size_t)head * S_TOT + sg) * 128;
#pragma unroll
    for (int k = 0; k < 16; ++k) {
      u16x8 u;
#pragma unroll
      for (int pp = 0; pp < 4; ++pp) {
        int d0 = k * 8 + pp * 2;
        float y0 = bf2f(xv[k][pp * 2]) * rn * wn[d0];
        float y1 = bf2f(xv[k][pp * 2 + 1]) * rn * wn[d0 + 1];
        int p = d0 >> 1;
        float f0 = fr[p * 4], f1 = fr[p * 4 + 1], f2v = fr[p * 4 + 2], f3 = fr[p * 4 + 3];
        u[pp * 2] = f2bf(f0 * y0 + f1 * y1);
        u[pp * 2 + 1] = f2bf(f2v * y0 + f3 * y1);
      }
      *(u16x8*)&Ob[ob + k * 8] = u;
    }
  } else {
    const int hv = tid >> 8, d = (tid & 255) >> 1, sh = tid & 1;
    const int head = h0 + hv;
    const int c = hv * 128 + d;
    size_t obase = ((size_t)head * 128 + d) * S_TOT + s_off + m0 + sh * 128;
#pragma unroll
    for (int v8 = 0; v8 < 16; ++v8) {
      u16x8 u;
#pragma unroll
      for (int i = 0; i < 8; ++i)
        u[i] = *(const unsigned short*)(smem + cta(sh * 128 + v8 * 8 + i, 2 * c));
      *(u16x8*)&Vt[obase + v8 * 8] = u;
    }
  }
}

// ---------------- 128x128 GEMM core (out projection), 2-buffer prefetch ----

struct StageSmem {
  unsigned short A[128 * 64];
  unsigned short B[128 * 64];
};

DEV void stage_tile(const char* A, const char* B, StageSmem* s, int kt, int tid) {
  const int row_s = tid >> 3;
  const int kbp = (tid & 7) * 16;
#pragma unroll
  for (int st = 0; st < 4; ++st) {
    int row = st * 32 + row_s;
    int kb = kbp ^ ((row & 7) << 4);
    gload16(A + (size_t)row * (DIMC * 2) + kt * 128 + kb, (char*)s->A + st * 4096 + tid * 16);
    gload16(B + (size_t)row * (DIMC * 2) + kt * 128 + kb, (char*)s->B + st * 4096 + tid * 16);
  }
}

DEV void gemm_core(const unsigned short* __restrict__ Ap,
                   const unsigned short* __restrict__ Bp,
                   StageSmem (&sm)[2], int tid, f32x4 (&acc)[4][4]) {
  const int wave = tid >> 6, lane = tid & 63;
  const int wr = wave >> 1, wc = wave & 1;
  const int lh = lane >> 4, ll = lane & 15;

  stage_tile((const char*)Ap, (const char*)Bp, &sm[0], 0, tid);
  __syncthreads();

  for (int kt = 0; kt < 48; ++kt) {
    if (kt + 1 < 48)  // issue prefetch BEFORE compute: full K-step of cover
      stage_tile((const char*)Ap, (const char*)Bp, &sm[(kt + 1) & 1], kt + 1, tid);
    const StageSmem* s = &sm[kt & 1];
#pragma unroll
    for (int ks = 0; ks < 2; ++ks) {
      s16x8 a[4], b[4];
#pragma unroll
      for (int f = 0; f < 4; ++f) {
        int ar = wr * 64 + f * 16 + ll;
        a[f] = *(const s16x8*)((const char*)s->A + ar * 128 +
                               ((ks * 64 + lh * 16) ^ ((ar & 7) << 4)));
        int br = wc * 64 + f * 16 + ll;
        b[f] = *(const s16x8*)((const char*)s->B + br * 128 +
                               ((ks * 64 + lh * 16) ^ ((br & 7) << 4)));
      }
#pragma unroll
      for (int i = 0; i < 4; i++)
#pragma unroll
        for (int j = 0; j < 4; j++)
          acc[i][j] = __builtin_amdgcn_mfma_f32_16x16x32_bf16(a[i], b[j], acc[i][j], 0, 0, 0);
    }
    __syncthreads();  // drains prefetch (covered by the MFMA above) + swaps
  }
}

__global__ __launch_bounds__(256, 2) void out_gemm(
    const unsigned short* __restrict__ A, const unsigned short* __restrict__ WT,
    const float* __restrict__ bias, float* __restrict__ C) {
  __shared__ StageSmem sm[2];
  const int tid = threadIdx.x;
  const int m0 = blockIdx.y * 128, n0 = blockIdx.x * 128;
  f32x4 acc[4][4] = {};
  gemm_core(A + (size_t)m0 * DIMC, WT + (size_t)n0 * DIMC, sm, tid, acc);
  const int wave = tid >> 6, lane = tid & 63;
  const int wr = wave >> 1, wc = wave & 1, lh = lane >> 4, ll = lane & 15;
#pragma unroll
  for (int fn = 0; fn < 4; ++fn) {
    int c = n0 + wc * 64 + fn * 16 + ll;
    float bv = bias[c];
#pragma unroll
    for (int fm = 0; fm < 4; ++fm)
#pragma unroll
      for (int j = 0; j < 4; j++) {
        int r = m0 + wr * 64 + fm * 16 + lh * 4 + j;
        C[(size_t)r * DIMC + c] = acc[fm][fn][j] + bv;
      }
  }
}

// ---------------- flash attention (unchanged) ----------------

__global__ __launch_bounds__(256, 2) void attn_k(
    const unsigned short* __restrict__ Qb, const unsigned short* __restrict__ Kb,
    const unsigned short* __restrict__ Vt, unsigned short* __restrict__ AO) {
  __shared__ alignas(128) unsigned short Ks[2][64 * 128];
  __shared__ alignas(128) unsigned short Vs[128 * 64];
  __shared__ alignas(128) unsigned short Ps[4][32 * 72];
  __shared__ float tabA[4][32];
  __shared__ float tabL[4][32];

  const int tid = threadIdx.x, w = tid >> 6, lane = tid & 63;
  const int lh = lane >> 4, ll16 = lane & 15;
  const int ll31 = lane & 31, hi = lane >> 5;
  const int wgid = blockIdx.x;
  const int nid = (wgid & 7) * 60 + (wgid >> 3);
  const int h = nid / 20, qt = nid % 20;
  const float C = 0.12751744f;  // (1/sqrt(128)) * log2(e)

  s16x8 qf[2][4];
#pragma unroll
  for (int rb = 0; rb < 2; rb++) {
    size_t qbase = ((size_t)h * S_TOT + qt * 128 + w * 32 + rb * 16 + ll16) * 128;
#pragma unroll
    for (int ks = 0; ks < 4; ks++) qf[rb][ks] = *(const s16x8*)&Qb[qbase + ks * 32 + lh * 8];
  }

  float m2[2][4], l_r[2][4];
  f32x16 o[4] = {};
#pragma unroll
  for (int rb = 0; rb < 2; rb++)
#pragma unroll
    for (int j = 0; j < 4; j++) { m2[rb][j] = -1e30f; l_r[rb][j] = 0.f; }

  const unsigned short* Kh = Kb + (size_t)h * S_TOT * 128;
  const unsigned short* Vh = Vt + (size_t)h * 128 * S_TOT;
  unsigned short* Pw = &Ps[w][0];

  {
#pragma unroll
    for (int st = 0; st < 4; ++st) {
      int row = st * 16 + (tid >> 4);
      int col = ((tid & 15) * 16) ^ ((row & 7) << 4);
      gload16((const char*)(Kh + (size_t)row * 128) + col,
              (char*)&Ks[0][0] + st * 4096 + tid * 16);
    }
  }

  int cur = 0;
  for (int kt = 0; kt < 40; ++kt) {
    __syncthreads();
    {
      const int k0 = kt * 64;
#pragma unroll
      for (int st = 0; st < 4; ++st) {
        int row = st * 32 + (tid >> 3);
        int col = ((tid & 7) * 16) ^ ((row & 7) << 4);
        gload16((const char*)(Vh + (size_t)row * S_TOT + k0) + col,
                (char*)Vs + st * 4096 + tid * 16);
      }
    }
    if (kt + 1 < 40) {
      const unsigned short* Kn = Kh + (size_t)(kt + 1) * 64 * 128;
#pragma unroll
      for (int st = 0; st < 4; ++st) {
        int row = st * 16 + (tid >> 4);
        int col = ((tid & 15) * 16) ^ ((row & 7) << 4);
        gload16((const char*)(Kn + (size_t)row * 128) + col,
                (char*)&Ks[cur ^ 1][0] + st * 4096 + tid * 16);
      }
    }

    const char* Kc = (const char*)&Ks[cur][0];
    f32x4 sc[2][4] = {};
#pragma unroll
    for (int kb = 0; kb < 4; kb++) {
      int krow = kb * 16 + ll16;
      const char* kr = Kc + krow * 256;
      int swz = (krow & 7) << 4;
#pragma unroll
      for (int ks = 0; ks < 4; ks++) {
        s16x8 bf = *(const s16x8*)(kr + ((ks * 64 + lh * 16) ^ swz));
        sc[0][kb] = __builtin_amdgcn_mfma_f32_16x16x32_bf16(qf[0][ks], bf, sc[0][kb], 0, 0, 0);
        sc[1][kb] = __builtin_amdgcn_mfma_f32_16x16x32_bf16(qf[1][ks], bf, sc[1][kb], 0, 0, 0);
      }
    }

    float pmax[2][4];
#pragma unroll
    for (int rb = 0; rb < 2; rb++)
#pragma unroll
      for (int j = 0; j < 4; j++) {
        float v = fmaxf(fmaxf(sc[rb][0][j], sc[rb][1][j]), fmaxf(sc[rb][2][j], sc[rb][3][j]));
        pmax[rb][j] = rowmax16(v) * C;
      }
    bool need = false;
#pragma unroll
    for (int rb = 0; rb < 2; rb++)
#pragma unroll
      for (int j = 0; j < 4; j++) need |= (pmax[rb][j] > m2[rb][j] + 8.0f);
    if (__any(need)) {
#pragma unroll
      for (int rb = 0; rb < 2; rb++)
#pragma unroll
        for (int j = 0; j < 4; j++) {
          float mn = fmaxf(m2[rb][j], pmax[rb][j]);
          float al = exp2_fast(m2[rb][j] - mn);
          m2[rb][j] = mn;
          l_r[rb][j] *= al;
          if (ll16 == 0) tabA[w][rb * 16 + lh * 4 + j] = al;
        }
#pragma unroll
      for (int reg = 0; reg < 16; reg++) {
        int cr = (reg & 3) + 8 * (reg >> 2) + 4 * hi;
        float alv = tabA[w][cr];
        o[0][reg] *= alv; o[1][reg] *= alv; o[2][reg] *= alv; o[3][reg] *= alv;
      }
    }
#pragma unroll
    for (int rb = 0; rb < 2; rb++) {
      float ps0 = 0.f, ps1 = 0.f, ps2 = 0.f, ps3 = 0.f;
#pragma unroll
      for (int kb = 0; kb < 4; kb++) {
        float p0 = exp2_fast(sc[rb][kb][0] * C - m2[rb][0]);
        float p1 = exp2_fast(sc[rb][kb][1] * C - m2[rb][1]);
        float p2 = exp2_fast(sc[rb][kb][2] * C - m2[rb][2]);
        float p3 = exp2_fast(sc[rb][kb][3] * C - m2[rb][3]);
        ps0 += p0; ps1 += p1; ps2 += p2; ps3 += p3;
        int rbase = (rb * 16 + lh * 4);
        Pw[(rbase + 0) * 72 + kb * 16 + ll16] = f2bf(p0);
        Pw[(rbase + 1) * 72 + kb * 16 + ll16] = f2bf(p1);
        Pw[(rbase + 2) * 72 + kb * 16 + ll16] = f2bf(p2);
        Pw[(rbase + 3) * 72 + kb * 16 + ll16] = f2bf(p3);
      }
      l_r[rb][0] += rowsum16(ps0);
      l_r[rb][1] += rowsum16(ps1);
      l_r[rb][2] += rowsum16(ps2);
      l_r[rb][3] += rowsum16(ps3);
    }

    __syncthreads();

#pragma unroll
    for (int kstep = 0; kstep < 4; kstep++) {
      s16x8 pa = *(const s16x8*)((const char*)Pw + ll31 * 144 + kstep * 32 + hi * 16);
#pragma unroll
      for (int dblk = 0; dblk < 4; dblk++) {
        int vrow = dblk * 32 + ll31;
        s16x8 vb = *(const s16x8*)((const char*)Vs + vrow * 128 +
                                   ((kstep * 32 + hi * 16) ^ ((vrow & 7) << 4)));
        o[dblk] = __builtin_amdgcn_mfma_f32_32x32x16_bf16(pa, vb, o[dblk], 0, 0, 0);
      }
    }
    cur ^= 1;
  }

  if (ll16 == 0) {
#pragma unroll
    for (int rb = 0; rb < 2; rb++)
#pragma unroll
      for (int j = 0; j < 4; j++) tabL[w][rb * 16 + lh * 4 + j] = l_r[rb][j];
  }
#pragma unroll
  for (int reg = 0; reg < 16; reg++) {
    int cr = (reg & 3) + 8 * (reg >> 2) + 4 * hi;
    float inv = 1.0f / tabL[w][cr];
    int srow = qt * 128 + w * 32 + cr;
    size_t base = (size_t)srow * DIMC + h * 128;
#pragma unroll
    for (int dblk = 0; dblk < 4; dblk++)
      AO[base + dblk * 32 + ll31] = f2bf(o[dblk][reg] * inv);
  }
}

// ---------------- launcher ----------------

extern "C" void kernel_launch(void* const* d_in, const int* in_sizes, int n_in,
                              void* d_out, int out_size, void* d_ws, size_t ws_size,
                              hipStream_t stream) {
  (void)in_sizes; (void)n_in; (void)out_size; (void)ws_size;
  const float* Xa = (const float*)d_in[0];
  const float* Xb = (const float*)d_in[1];
  const float* freqs = (const float*)d_in[2];
  const float* Wqkv_a = (const float*)d_in[3];
  const float* bqkv_a = (const float*)d_in[4];
  const float* Wqkv_b = (const float*)d_in[5];
  const float* bqkv_b = (const float*)d_in[6];
  const float* wq_a = (const float*)d_in[7];
  const float* wk_a = (const float*)d_in[8];
  const float* wq_b = (const float*)d_in[9];
  const float* wk_b = (const float*)d_in[10];
  const float* Wout_a = (const float*)d_in[11];
  const float* bout_a = (const float*)d_in[12];
  const float* Wout_b = (const float*)d_in[13];
  const float* bout_b = (const float*)d_in[14];
  float* out = (float*)d_out;

  char* ws = (char*)d_ws;
  unsigned short* WTa  = (unsigned short*)ws; ws += (size_t)NQKV * DIMC * 2;
  unsigned short* WTb  = (unsigned short*)ws; ws += (size_t)NQKV * DIMC * 2;
  unsigned short* WoTa = (unsigned short*)ws; ws += (size_t)DIMC * DIMC * 2;
  unsigned short* WoTb = (unsigned short*)ws; ws += (size_t)DIMC * DIMC * 2;
  unsigned short* Xa16 = (unsigned short*)ws; ws += (size_t)2048 * DIMC * 2;
  unsigned short* Xb16 = (unsigned short*)ws; ws += (size_t)512 * DIMC * 2;
  unsigned short* Qb   = (unsigned short*)ws; ws += (size_t)24 * S_TOT * 128 * 2;
  unsigned short* Kbf  = (unsigned short*)ws; ws += (size_t)24 * S_TOT * 128 * 2;
  unsigned short* Vt   = (unsigned short*)ws; ws += (size_t)24 * S_TOT * 128 * 2;
  unsigned short* AO   = (unsigned short*)ws; ws += (size_t)S_TOT * DIMC * 2;

  cvt_bf16_k<<<dim3(2048 * DIMC / 8 / 256), dim3(256), 0, stream>>>(Xa, Xa16, 2048 * DIMC / 8);
  cvt_bf16_k<<<dim3(512 * DIMC / 8 / 256), dim3(256), 0, stream>>>(Xb, Xb16, 512 * DIMC / 8);
  transpose_cvt<<<dim3(NQKV / 64, DIMC / 64), dim3(256), 0, stream>>>(Wqkv_a, WTa, DIMC, NQKV);
  transpose_cvt<<<dim3(NQKV / 64, DIMC / 64), dim3(256), 0, stream>>>(Wqkv_b, WTb, DIMC, NQKV);
  transpose_cvt<<<dim3(DIMC / 64, DIMC / 64), dim3(256), 0, stream>>>(Wout_a, WoTa, DIMC, DIMC);
  transpose_cvt<<<dim3(DIMC / 64, DIMC / 64), dim3(256), 0, stream>>>(Wout_b, WoTb, DIMC, DIMC);

  qkv256<<<dim3(360), dim3(512), 0, stream>>>(Xa16, Xb16, WTa, WTb, bqkv_a, bqkv_b,
                                              wq_a, wk_a, wq_b, wk_b, freqs,
                                              Qb, Kbf, Vt, 288, 36);

  attn_k<<<dim3(480), dim3(256), 0, stream>>>(Qb, Kbf, Vt, AO);

  out_gemm<<<dim3(24, 16), dim3(256), 0, stream>>>(AO + (size_t)512 * DIMC, WoTa, bout_a, out);
  out_gemm<<<dim3(24, 4), dim3(256), 0, stream>>>(AO, WoTb, bout_b, out + (size_t)2048 * DIMC);
}

// Round 5
// 614.518 us; speedup vs baseline: 1.0663x; 1.0397x over previous
//
#include <hip/hip_runtime.h>
#include <hip/hip_bf16.h>

// FluxJointAttention on MI355X (gfx950), bf16 MFMA pipeline.
// Round 5: qkv256 K-loop rebuilt as 4 quadrant-phases with COUNTED vmcnt(2)
// (loads stay in flight across barriers; the m218 lever). Staging ledger:
//   p0(c): A1,B0,B1 of tile c+1 -> idle buffer (free since tile c-1)
//   p3(c): A0 of tile c+2 -> active buffer A0-region (last read at p2)
//   p3(c): s_waitcnt vmcnt(2) before end-barrier (tail: vmcnt(0))
// attn / out_gemm / conversions unchanged.

typedef __attribute__((ext_vector_type(8))) short s16x8;
typedef __attribute__((ext_vector_type(8))) unsigned short u16x8;
typedef __attribute__((ext_vector_type(4))) float f32x4;
typedef __attribute__((ext_vector_type(16))) float f32x16;

#define DEV static __device__ __forceinline__

#define S_TOT 2560
#define DIMC 3072
#define NQKV 9216

DEV unsigned short f2bf(float f) {
  union { float f; unsigned u; } v; v.f = f;
  return (unsigned short)((v.u + 0x7fffu + ((v.u >> 16) & 1u)) >> 16);
}
DEV float bf2f(unsigned short h) {
  union { unsigned u; float f; } v; v.u = ((unsigned)h) << 16;
  return v.f;
}
DEV void gload16(const void* g, void* l) {
  __builtin_amdgcn_global_load_lds((__attribute__((address_space(1))) void*)g,
                                   (__attribute__((address_space(3))) void*)l,
                                   16, 0, 0);
}
template <int N>
DEV void wait_vm() { asm volatile("s_waitcnt vmcnt(%0)" :: "n"(N) : "memory"); }
DEV float exp2_fast(float x) {
#if __has_builtin(__builtin_amdgcn_exp2f)
  return __builtin_amdgcn_exp2f(x);
#else
  return __expf(x * 0.69314718056f);
#endif
}
template <int CTRL>
DEV float dppf(float x) {
  return __int_as_float(__builtin_amdgcn_update_dpp(0, __float_as_int(x), CTRL, 0xf, 0xf, true));
}
DEV float rowmax16(float x) {
  x = fmaxf(x, dppf<0xB1>(x));
  x = fmaxf(x, dppf<0x4E>(x));
  x = fmaxf(x, dppf<0x141>(x));
  x = fmaxf(x, dppf<0x140>(x));
  return x;
}
DEV float rowsum16(float x) {
  x += dppf<0xB1>(x);
  x += dppf<0x4E>(x);
  x += dppf<0x141>(x);
  x += dppf<0x140>(x);
  return x;
}

// ---------------- conversion kernels ----------------

__global__ __launch_bounds__(256) void cvt_bf16_k(const float* __restrict__ in,
                                                  unsigned short* __restrict__ out,
                                                  int n8) {
  int i = blockIdx.x * 256 + threadIdx.x;
  if (i >= n8) return;
  const float4* p = (const float4*)(in + (size_t)i * 8);
  float4 a = p[0], b = p[1];
  u16x8 u;
  u[0] = f2bf(a.x); u[1] = f2bf(a.y); u[2] = f2bf(a.z); u[3] = f2bf(a.w);
  u[4] = f2bf(b.x); u[5] = f2bf(b.y); u[6] = f2bf(b.z); u[7] = f2bf(b.w);
  *(u16x8*)(out + (size_t)i * 8) = u;
}

__global__ __launch_bounds__(256) void transpose_cvt(const float* __restrict__ W,
                                                     unsigned short* __restrict__ WT,
                                                     int K, int N) {
  __shared__ float tile[64][65];
  const int t = threadIdx.x;
  const int n0 = blockIdx.x * 64, k0 = blockIdx.y * 64;
#pragma unroll
  for (int rep = 0; rep < 4; ++rep) {
    int idx = rep * 256 + t;
    int r = idx >> 4, c4 = (idx & 15) * 4;
    float4 v = *(const float4*)&W[(size_t)(k0 + r) * N + n0 + c4];
    tile[r][c4] = v.x; tile[r][c4 + 1] = v.y; tile[r][c4 + 2] = v.z; tile[r][c4 + 3] = v.w;
  }
  __syncthreads();
#pragma unroll
  for (int rep = 0; rep < 2; ++rep) {
    int idx = rep * 256 + t;
    int j = idx >> 3, i0 = (idx & 7) * 8;
    u16x8 u;
#pragma unroll
    for (int i = 0; i < 8; i++) u[i] = f2bf(tile[i0 + i][j]);
    *(u16x8*)&WT[(size_t)(n0 + j) * K + k0 + i0] = u;
  }
}

// ======== 256x256 8-wave QKV GEMM, counted-vmcnt pipeline ========

DEV int cta(int r, int cb) {  // epilogue C-tile: 512B rows, XOR bits 5-8 by row&15
  return (r << 9) + (cb ^ ((r & 15) << 5));
}

DEV void stage_half(const char* panel128, char* dst16k, int kt, int tid) {
  int slot = tid & 7;
  int r = tid >> 3;  // 0..63
#pragma unroll
  for (int l = 0; l < 2; ++l) {
    int row = r + l * 64;
    gload16(panel128 + (size_t)row * 6144 + kt * 128 + ((slot * 16) ^ ((row & 7) << 4)),
            dst16k + (l * 512 + tid) * 16);
  }
}

__global__ __launch_bounds__(512, 2) void qkv256(
    const unsigned short* __restrict__ A0p, const unsigned short* __restrict__ A1p,
    const unsigned short* __restrict__ W0, const unsigned short* __restrict__ W1,
    const float* __restrict__ b0, const float* __restrict__ b1,
    const float* __restrict__ wqa, const float* __restrict__ wka,
    const float* __restrict__ wqb, const float* __restrict__ wkb,
    const float* __restrict__ freqs,
    unsigned short* __restrict__ Qb, unsigned short* __restrict__ Kb,
    unsigned short* __restrict__ Vt, int nt0, int ncols) {
  __shared__ __align__(128) char smem[131072];
  const int tid = threadIdx.x;
  const int w = tid >> 6, lane = tid & 63;
  const int wr = w >> 2, wc = w & 3;
  const int lh = lane >> 4, ll = lane & 15;

  const int chunk = gridDim.x >> 3;
  const int nid = ((int)blockIdx.x & 7) * chunk + ((int)blockIdx.x >> 3);
  const int strm = (nid >= nt0) ? 1 : 0;
  const int t = strm ? nid - nt0 : nid;
  const int m0 = (t / ncols) * 256, n0 = (t % ncols) * 256;
  const char* ApC = (const char*)((strm ? A1p : A0p) + (size_t)m0 * DIMC);
  const char* BpC = (const char*)((strm ? W1 : W0) + (size_t)n0 * DIMC);
  const float* biasp = (strm ? b1 : b0) + n0;
  const int s_off = strm ? 0 : 512;

  f32x4 acc[8][4] = {};

  // ---- prologue: tile0 all halves -> buf0, A0(1) -> buf1; keep A0(1) flying
  stage_half(ApC, smem, 0, tid);
  stage_half(ApC + 128 * 6144, smem + 16384, 0, tid);
  stage_half(BpC, smem + 32768, 0, tid);
  stage_half(BpC + 128 * 6144, smem + 49152, 0, tid);
  stage_half(ApC, smem + 65536, 1, tid);
  wait_vm<2>();
  __builtin_amdgcn_s_barrier();

  int cur = 0;
  for (int c = 0; c < 48; ++c) {
    const char* Ab = smem + cur * 65536;
    const char* Bb = Ab + 32768;
    char* Nb = smem + (cur ^ 1) * 65536;
    s16x8 a[4][2], bA[2][2], bB[2][2];

    // ---- phase 0: reads a(mh0)+bA; stage A1,B0,B1 of c+1 ----
#pragma unroll
    for (int f = 0; f < 4; ++f) {
      int ar = wr * 128 + f * 16 + ll;
#pragma unroll
      for (int ks = 0; ks < 2; ++ks)
        a[f][ks] = *(const s16x8*)(Ab + ar * 128 + ((ks * 64 + lh * 16) ^ ((ar & 7) << 4)));
    }
#pragma unroll
    for (int g = 0; g < 2; ++g) {
      int br = wc * 64 + g * 16 + ll;
#pragma unroll
      for (int ks = 0; ks < 2; ++ks)
        bA[g][ks] = *(const s16x8*)(Bb + br * 128 + ((ks * 64 + lh * 16) ^ ((br & 7) << 4)));
    }
    if (c + 1 < 48) {
      stage_half(ApC + 128 * 6144, Nb + 16384, c + 1, tid);
      stage_half(BpC, Nb + 32768, c + 1, tid);
      stage_half(BpC + 128 * 6144, Nb + 49152, c + 1, tid);
    }
    __builtin_amdgcn_s_barrier();
    __builtin_amdgcn_s_setprio(1);
#pragma unroll
    for (int f = 0; f < 4; ++f)
#pragma unroll
      for (int g = 0; g < 2; ++g)
#pragma unroll
        for (int ks = 0; ks < 2; ++ks)
          acc[f][g] = __builtin_amdgcn_mfma_f32_16x16x32_bf16(a[f][ks], bA[g][ks], acc[f][g], 0, 0, 0);
    __builtin_amdgcn_s_setprio(0);
    __builtin_amdgcn_s_barrier();

    // ---- phase 1: reads bB ----
#pragma unroll
    for (int g = 0; g < 2; ++g) {
      int br = wc * 64 + 32 + g * 16 + ll;
#pragma unroll
      for (int ks = 0; ks < 2; ++ks)
        bB[g][ks] = *(const s16x8*)(Bb + br * 128 + ((ks * 64 + lh * 16) ^ ((br & 7) << 4)));
    }
    __builtin_amdgcn_s_barrier();
    __builtin_amdgcn_s_setprio(1);
#pragma unroll
    for (int f = 0; f < 4; ++f)
#pragma unroll
      for (int g = 0; g < 2; ++g)
#pragma unroll
        for (int ks = 0; ks < 2; ++ks)
          acc[f][2 + g] = __builtin_amdgcn_mfma_f32_16x16x32_bf16(a[f][ks], bB[g][ks], acc[f][2 + g], 0, 0, 0);
    __builtin_amdgcn_s_setprio(0);
    __builtin_amdgcn_s_barrier();

    // ---- phase 2: reads a(mh1) ----
#pragma unroll
    for (int f = 0; f < 4; ++f) {
      int ar = wr * 128 + 64 + f * 16 + ll;
#pragma unroll
      for (int ks = 0; ks < 2; ++ks)
        a[f][ks] = *(const s16x8*)(Ab + ar * 128 + ((ks * 64 + lh * 16) ^ ((ar & 7) << 4)));
    }
    __builtin_amdgcn_s_barrier();
    __builtin_amdgcn_s_setprio(1);
#pragma unroll
    for (int f = 0; f < 4; ++f)
#pragma unroll
      for (int g = 0; g < 2; ++g)
#pragma unroll
        for (int ks = 0; ks < 2; ++ks)
          acc[4 + f][g] = __builtin_amdgcn_mfma_f32_16x16x32_bf16(a[f][ks], bA[g][ks], acc[4 + f][g], 0, 0, 0);
    __builtin_amdgcn_s_setprio(0);
    __builtin_amdgcn_s_barrier();

    // ---- phase 3: stage A0(c+2) into active buf (A-region free after p2);
    //      counted vmcnt before end-barrier ----
    const bool st3 = (c + 2 < 48);
    if (st3) stage_half(ApC, smem + cur * 65536, c + 2, tid);
    __builtin_amdgcn_s_barrier();
    __builtin_amdgcn_s_setprio(1);
#pragma unroll
    for (int f = 0; f < 4; ++f)
#pragma unroll
      for (int g = 0; g < 2; ++g)
#pragma unroll
        for (int ks = 0; ks < 2; ++ks)
          acc[4 + f][2 + g] = __builtin_amdgcn_mfma_f32_16x16x32_bf16(a[f][ks], bB[g][ks], acc[4 + f][2 + g], 0, 0, 0);
    __builtin_amdgcn_s_setprio(0);
    if (st3) wait_vm<2>(); else wait_vm<0>();
    __builtin_amdgcn_s_barrier();
    cur ^= 1;
  }

  __syncthreads();
  // ---- epilogue: acc + bias -> swizzled bf16 ctile (reuse smem) ----
#pragma unroll
  for (int fn = 0; fn < 4; ++fn) {
    int c = wc * 64 + fn * 16 + ll;
    float bv = biasp[c];
#pragma unroll
    for (int fm = 0; fm < 8; ++fm)
#pragma unroll
      for (int j = 0; j < 4; ++j) {
        int r = wr * 128 + fm * 16 + lh * 4 + j;
        *(unsigned short*)(smem + cta(r, 2 * c)) = f2bf(acc[fm][fn][j] + bv);
      }
  }
  __syncthreads();

  const int qkvi = n0 / DIMC;
  const int h0 = (n0 % DIMC) / 128;

  if (qkvi < 2) {
    const float* wn = (qkvi == 0) ? (strm ? wqb : wqa) : (strm ? wkb : wka);
    unsigned short* Ob = (qkvi == 0) ? Qb : Kb;
    const int row = tid >> 1, hc = tid & 1;
    const int sg = s_off + m0 + row;
    const int head = h0 + hc;
    u16x8 xv[16];
    float ss = 0.f;
#pragma unroll
    for (int k = 0; k < 16; ++k) {
      xv[k] = *(const u16x8*)(smem + cta(row, hc * 256 + k * 16));
#pragma unroll
      for (int i = 0; i < 8; ++i) { float v = bf2f(xv[k][i]); ss += v * v; }
    }
    const float rn = rsqrtf(ss * (1.f / 128.f) + 1e-6f);
    const float* fr = freqs + (size_t)sg * 256;
    size_t ob = ((size_t)head * S_TOT + sg) * 128;
#pragma unroll
    for (int k = 0; k < 16; ++k) {
      u16x8 u;
#pragma unroll
      for (int pp = 0; pp < 4; ++pp) {
        int d0 = k * 8 + pp * 2;
        float y0 = bf2f(xv[k][pp * 2]) * rn * wn[d0];
        float y1 = bf2f(xv[k][pp * 2 + 1]) * rn * wn[d0 + 1];
        int p = d0 >> 1;
        float f0 = fr[p * 4], f1 = fr[p * 4 + 1], f2v = fr[p * 4 + 2], f3 = fr[p * 4 + 3];
        u[pp * 2] = f2bf(f0 * y0 + f1 * y1);
        u[pp * 2 + 1] = f2bf(f2v * y0 + f3 * y1);
      }
      *(u16x8*)&Ob[ob + k * 8] = u;
    }
  } else {
    const int hv = tid >> 8, d = (tid & 255) >> 1, sh = tid & 1;
    const int head = h0 + hv;
    const int c = hv * 128 + d;
    size_t obase = ((size_t)head * 128 + d) * S_TOT + s_off + m0 + sh * 128;
#pragma unroll
    for (int v8 = 0; v8 < 16; ++v8) {
      u16x8 u;
#pragma unroll
      for (int i = 0; i < 8; ++i)
        u[i] = *(const unsigned short*)(smem + cta(sh * 128 + v8 * 8 + i, 2 * c));
      *(u16x8*)&Vt[obase + v8 * 8] = u;
    }
  }
}

// ---------------- 128x128 GEMM core (out projection), 2-buffer prefetch ----

struct StageSmem {
  unsigned short A[128 * 64];
  unsigned short B[128 * 64];
};

DEV void stage_tile(const char* A, const char* B, StageSmem* s, int kt, int tid) {
  const int row_s = tid >> 3;
  const int kbp = (tid & 7) * 16;
#pragma unroll
  for (int st = 0; st < 4; ++st) {
    int row = st * 32 + row_s;
    int kb = kbp ^ ((row & 7) << 4);
    gload16(A + (size_t)row * (DIMC * 2) + kt * 128 + kb, (char*)s->A + st * 4096 + tid * 16);
    gload16(B + (size_t)row * (DIMC * 2) + kt * 128 + kb, (char*)s->B + st * 4096 + tid * 16);
  }
}

DEV void gemm_core(const unsigned short* __restrict__ Ap,
                   const unsigned short* __restrict__ Bp,
                   StageSmem (&sm)[2], int tid, f32x4 (&acc)[4][4]) {
  const int wave = tid >> 6, lane = tid & 63;
  const int wr = wave >> 1, wc = wave & 1;
  const int lh = lane >> 4, ll = lane & 15;

  stage_tile((const char*)Ap, (const char*)Bp, &sm[0], 0, tid);
  __syncthreads();

  for (int kt = 0; kt < 48; ++kt) {
    if (kt + 1 < 48)
      stage_tile((const char*)Ap, (const char*)Bp, &sm[(kt + 1) & 1], kt + 1, tid);
    const StageSmem* s = &sm[kt & 1];
#pragma unroll
    for (int ks = 0; ks < 2; ++ks) {
      s16x8 a[4], b[4];
#pragma unroll
      for (int f = 0; f < 4; ++f) {
        int ar = wr * 64 + f * 16 + ll;
        a[f] = *(const s16x8*)((const char*)s->A + ar * 128 +
                               ((ks * 64 + lh * 16) ^ ((ar & 7) << 4)));
        int br = wc * 64 + f * 16 + ll;
        b[f] = *(const s16x8*)((const char*)s->B + br * 128 +
                               ((ks * 64 + lh * 16) ^ ((br & 7) << 4)));
      }
#pragma unroll
      for (int i = 0; i < 4; i++)
#pragma unroll
        for (int j = 0; j < 4; j++)
          acc[i][j] = __builtin_amdgcn_mfma_f32_16x16x32_bf16(a[i], b[j], acc[i][j], 0, 0, 0);
    }
    __syncthreads();
  }
}

__global__ __launch_bounds__(256, 2) void out_gemm(
    const unsigned short* __restrict__ A, const unsigned short* __restrict__ WT,
    const float* __restrict__ bias, float* __restrict__ C) {
  __shared__ StageSmem sm[2];
  const int tid = threadIdx.x;
  const int m0 = blockIdx.y * 128, n0 = blockIdx.x * 128;
  f32x4 acc[4][4] = {};
  gemm_core(A + (size_t)m0 * DIMC, WT + (size_t)n0 * DIMC, sm, tid, acc);
  const int wave = tid >> 6, lane = tid & 63;
  const int wr = wave >> 1, wc = wave & 1, lh = lane >> 4, ll = lane & 15;
#pragma unroll
  for (int fn = 0; fn < 4; ++fn) {
    int c = n0 + wc * 64 + fn * 16 + ll;
    float bv = bias[c];
#pragma unroll
    for (int fm = 0; fm < 4; ++fm)
#pragma unroll
      for (int j = 0; j < 4; j++) {
        int r = m0 + wr * 64 + fm * 16 + lh * 4 + j;
        C[(size_t)r * DIMC + c] = acc[fm][fn][j] + bv;
      }
  }
}

// ---------------- flash attention (unchanged) ----------------

__global__ __launch_bounds__(256, 2) void attn_k(
    const unsigned short* __restrict__ Qb, const unsigned short* __restrict__ Kb,
    const unsigned short* __restrict__ Vt, unsigned short* __restrict__ AO) {
  __shared__ alignas(128) unsigned short Ks[2][64 * 128];
  __shared__ alignas(128) unsigned short Vs[128 * 64];
  __shared__ alignas(128) unsigned short Ps[4][32 * 72];
  __shared__ float tabA[4][32];
  __shared__ float tabL[4][32];

  const int tid = threadIdx.x, w = tid >> 6, lane = tid & 63;
  const int lh = lane >> 4, ll16 = lane & 15;
  const int ll31 = lane & 31, hi = lane >> 5;
  const int wgid = blockIdx.x;
  const int nid = (wgid & 7) * 60 + (wgid >> 3);
  const int h = nid / 20, qt = nid % 20;
  const float C = 0.12751744f;  // (1/sqrt(128)) * log2(e)

  s16x8 qf[2][4];
#pragma unroll
  for (int rb = 0; rb < 2; rb++) {
    size_t qbase = ((size_t)h * S_TOT + qt * 128 + w * 32 + rb * 16 + ll16) * 128;
#pragma unroll
    for (int ks = 0; ks < 4; ks++) qf[rb][ks] = *(const s16x8*)&Qb[qbase + ks * 32 + lh * 8];
  }

  float m2[2][4], l_r[2][4];
  f32x16 o[4] = {};
#pragma unroll
  for (int rb = 0; rb < 2; rb++)
#pragma unroll
    for (int j = 0; j < 4; j++) { m2[rb][j] = -1e30f; l_r[rb][j] = 0.f; }

  const unsigned short* Kh = Kb + (size_t)h * S_TOT * 128;
  const unsigned short* Vh = Vt + (size_t)h * 128 * S_TOT;
  unsigned short* Pw = &Ps[w][0];

  {
#pragma unroll
    for (int st = 0; st < 4; ++st) {
      int row = st * 16 + (tid >> 4);
      int col = ((tid & 15) * 16) ^ ((row & 7) << 4);
      gload16((const char*)(Kh + (size_t)row * 128) + col,
              (char*)&Ks[0][0] + st * 4096 + tid * 16);
    }
  }

  int cur = 0;
  for (int kt = 0; kt < 40; ++kt) {
    __syncthreads();
    {
      const int k0 = kt * 64;
#pragma unroll
      for (int st = 0; st < 4; ++st) {
        int row = st * 32 + (tid >> 3);
        int col = ((tid & 7) * 16) ^ ((row & 7) << 4);
        gload16((const char*)(Vh + (size_t)row * S_TOT + k0) + col,
                (char*)Vs + st * 4096 + tid * 16);
      }
    }
    if (kt + 1 < 40) {
      const unsigned short* Kn = Kh + (size_t)(kt + 1) * 64 * 128;
#pragma unroll
      for (int st = 0; st < 4; ++st) {
        int row = st * 16 + (tid >> 4);
        int col = ((tid & 15) * 16) ^ ((row & 7) << 4);
        gload16((const char*)(Kn + (size_t)row * 128) + col,
                (char*)&Ks[cur ^ 1][0] + st * 4096 + tid * 16);
      }
    }

    const char* Kc = (const char*)&Ks[cur][0];
    f32x4 sc[2][4] = {};
#pragma unroll
    for (int kb = 0; kb < 4; kb++) {
      int krow = kb * 16 + ll16;
      const char* kr = Kc + krow * 256;
      int swz = (krow & 7) << 4;
#pragma unroll
      for (int ks = 0; ks < 4; ks++) {
        s16x8 bf = *(const s16x8*)(kr + ((ks * 64 + lh * 16) ^ swz));
        sc[0][kb] = __builtin_amdgcn_mfma_f32_16x16x32_bf16(qf[0][ks], bf, sc[0][kb], 0, 0, 0);
        sc[1][kb] = __builtin_amdgcn_mfma_f32_16x16x32_bf16(qf[1][ks], bf, sc[1][kb], 0, 0, 0);
      }
    }

    float pmax[2][4];
#pragma unroll
    for (int rb = 0; rb < 2; rb++)
#pragma unroll
      for (int j = 0; j < 4; j++) {
        float v = fmaxf(fmaxf(sc[rb][0][j], sc[rb][1][j]), fmaxf(sc[rb][2][j], sc[rb][3][j]));
        pmax[rb][j] = rowmax16(v) * C;
      }
    bool need = false;
#pragma unroll
    for (int rb = 0; rb < 2; rb++)
#pragma unroll
      for (int j = 0; j < 4; j++) need |= (pmax[rb][j] > m2[rb][j] + 8.0f);
    if (__any(need)) {
#pragma unroll
      for (int rb = 0; rb < 2; rb++)
#pragma unroll
        for (int j = 0; j < 4; j++) {
          float mn = fmaxf(m2[rb][j], pmax[rb][j]);
          float al = exp2_fast(m2[rb][j] - mn);
          m2[rb][j] = mn;
          l_r[rb][j] *= al;
          if (ll16 == 0) tabA[w][rb * 16 + lh * 4 + j] = al;
        }
#pragma unroll
      for (int reg = 0; reg < 16; reg++) {
        int cr = (reg & 3) + 8 * (reg >> 2) + 4 * hi;
        float alv = tabA[w][cr];
        o[0][reg] *= alv; o[1][reg] *= alv; o[2][reg] *= alv; o[3][reg] *= alv;
      }
    }
#pragma unroll
    for (int rb = 0; rb < 2; rb++) {
      float ps0 = 0.f, ps1 = 0.f, ps2 = 0.f, ps3 = 0.f;
#pragma unroll
      for (int kb = 0; kb < 4; kb++) {
        float p0 = exp2_fast(sc[rb][kb][0] * C - m2[rb][0]);
        float p1 = exp2_fast(sc[rb][kb][1] * C - m2[rb][1]);
        float p2 = exp2_fast(sc[rb][kb][2] * C - m2[rb][2]);
        float p3 = exp2_fast(sc[rb][kb][3] * C - m2[rb][3]);
        ps0 += p0; ps1 += p1; ps2 += p2; ps3 += p3;
        int rbase = (rb * 16 + lh * 4);
        Pw[(rbase + 0) * 72 + kb * 16 + ll16] = f2bf(p0);
        Pw[(rbase + 1) * 72 + kb * 16 + ll16] = f2bf(p1);
        Pw[(rbase + 2) * 72 + kb * 16 + ll16] = f2bf(p2);
        Pw[(rbase + 3) * 72 + kb * 16 + ll16] = f2bf(p3);
      }
      l_r[rb][0] += rowsum16(ps0);
      l_r[rb][1] += rowsum16(ps1);
      l_r[rb][2] += rowsum16(ps2);
      l_r[rb][3] += rowsum16(ps3);
    }

    __syncthreads();

#pragma unroll
    for (int kstep = 0; kstep < 4; kstep++) {
      s16x8 pa = *(const s16x8*)((const char*)Pw + ll31 * 144 + kstep * 32 + hi * 16);
#pragma unroll
      for (int dblk = 0; dblk < 4; dblk++) {
        int vrow = dblk * 32 + ll31;
        s16x8 vb = *(const s16x8*)((const char*)Vs + vrow * 128 +
                                   ((kstep * 32 + hi * 16) ^ ((vrow & 7) << 4)));
        o[dblk] = __builtin_amdgcn_mfma_f32_32x32x16_bf16(pa, vb, o[dblk], 0, 0, 0);
      }
    }
    cur ^= 1;
  }

  if (ll16 == 0) {
#pragma unroll
    for (int rb = 0; rb < 2; rb++)
#pragma unroll
      for (int j = 0; j < 4; j++) tabL[w][rb * 16 + lh * 4 + j] = l_r[rb][j];
  }
#pragma unroll
  for (int reg = 0; reg < 16; reg++) {
    int cr = (reg & 3) + 8 * (reg >> 2) + 4 * hi;
    float inv = 1.0f / tabL[w][cr];
    int srow = qt * 128 + w * 32 + cr;
    size_t base = (size_t)srow * DIMC + h * 128;
#pragma unroll
    for (int dblk = 0; dblk < 4; dblk++)
      AO[base + dblk * 32 + ll31] = f2bf(o[dblk][reg] * inv);
  }
}

// ---------------- launcher ----------------

extern "C" void kernel_launch(void* const* d_in, const int* in_sizes, int n_in,
                              void* d_out, int out_size, void* d_ws, size_t ws_size,
                              hipStream_t stream) {
  (void)in_sizes; (void)n_in; (void)out_size; (void)ws_size;
  const float* Xa = (const float*)d_in[0];
  const float* Xb = (const float*)d_in[1];
  const float* freqs = (const float*)d_in[2];
  const float* Wqkv_a = (const float*)d_in[3];
  const float* bqkv_a = (const float*)d_in[4];
  const float* Wqkv_b = (const float*)d_in[5];
  const float* bqkv_b = (const float*)d_in[6];
  const float* wq_a = (const float*)d_in[7];
  const float* wk_a = (const float*)d_in[8];
  const float* wq_b = (const float*)d_in[9];
  const float* wk_b = (const float*)d_in[10];
  const float* Wout_a = (const float*)d_in[11];
  const float* bout_a = (const float*)d_in[12];
  const float* Wout_b = (const float*)d_in[13];
  const float* bout_b = (const float*)d_in[14];
  float* out = (float*)d_out;

  char* ws = (char*)d_ws;
  unsigned short* WTa  = (unsigned short*)ws; ws += (size_t)NQKV * DIMC * 2;
  unsigned short* WTb  = (unsigned short*)ws; ws += (size_t)NQKV * DIMC * 2;
  unsigned short* WoTa = (unsigned short*)ws; ws += (size_t)DIMC * DIMC * 2;
  unsigned short* WoTb = (unsigned short*)ws; ws += (size_t)DIMC * DIMC * 2;
  unsigned short* Xa16 = (unsigned short*)ws; ws += (size_t)2048 * DIMC * 2;
  unsigned short* Xb16 = (unsigned short*)ws; ws += (size_t)512 * DIMC * 2;
  unsigned short* Qb   = (unsigned short*)ws; ws += (size_t)24 * S_TOT * 128 * 2;
  unsigned short* Kbf  = (unsigned short*)ws; ws += (size_t)24 * S_TOT * 128 * 2;
  unsigned short* Vt   = (unsigned short*)ws; ws += (size_t)24 * S_TOT * 128 * 2;
  unsigned short* AO   = (unsigned short*)ws; ws += (size_t)S_TOT * DIMC * 2;

  cvt_bf16_k<<<dim3(2048 * DIMC / 8 / 256), dim3(256), 0, stream>>>(Xa, Xa16, 2048 * DIMC / 8);
  cvt_bf16_k<<<dim3(512 * DIMC / 8 / 256), dim3(256), 0, stream>>>(Xb, Xb16, 512 * DIMC / 8);
  transpose_cvt<<<dim3(NQKV / 64, DIMC / 64), dim3(256), 0, stream>>>(Wqkv_a, WTa, DIMC, NQKV);
  transpose_cvt<<<dim3(NQKV / 64, DIMC / 64), dim3(256), 0, stream>>>(Wqkv_b, WTb, DIMC, NQKV);
  transpose_cvt<<<dim3(DIMC / 64, DIMC / 64), dim3(256), 0, stream>>>(Wout_a, WoTa, DIMC, DIMC);
  transpose_cvt<<<dim3(DIMC / 64, DIMC / 64), dim3(256), 0, stream>>>(Wout_b, WoTb, DIMC, DIMC);

  qkv256<<<dim3(360), dim3(512), 0, stream>>>(Xa16, Xb16, WTa, WTb, bqkv_a, bqkv_b,
                                              wq_a, wk_a, wq_b, wk_b, freqs,
                                              Qb, Kbf, Vt, 288, 36);

  attn_k<<<dim3(480), dim3(256), 0, stream>>>(Qb, Kbf, Vt, AO);

  out_gemm<<<dim3(24, 16), dim3(256), 0, stream>>>(AO + (size_t)512 * DIMC, WoTa, bout_a, out);
  out_gemm<<<dim3(24, 4), dim3(256), 0, stream>>>(AO, WoTb, bout_b, out + (size_t)2048 * DIMC);
}

// Round 6
// 487.223 us; speedup vs baseline: 1.3449x; 1.2613x over previous
//
#include <hip/hip_runtime.h>
#include <hip/hip_bf16.h>

// FluxJointAttention on MI355X (gfx950), bf16 MFMA pipeline.
// Round 6: qkv back to 128^2 tiles (1440 blocks, 94% packing) using the
// PROVEN prefetch-before-compute 2-phase core (the r4 out_gemm core, ~760 TF
// effective measured in-workload). Fused bias/RMS/RoPE/V^T epilogue kept.
// out_gemm: both streams merged into one 480-block launch. attn unchanged.

typedef __attribute__((ext_vector_type(8))) short s16x8;
typedef __attribute__((ext_vector_type(8))) unsigned short u16x8;
typedef __attribute__((ext_vector_type(4))) float f32x4;
typedef __attribute__((ext_vector_type(16))) float f32x16;

#define DEV static __device__ __forceinline__

#define S_TOT 2560
#define DIMC 3072
#define NQKV 9216

DEV unsigned short f2bf(float f) {
  union { float f; unsigned u; } v; v.f = f;
  return (unsigned short)((v.u + 0x7fffu + ((v.u >> 16) & 1u)) >> 16);
}
DEV float bf2f(unsigned short h) {
  union { unsigned u; float f; } v; v.u = ((unsigned)h) << 16;
  return v.f;
}
DEV void gload16(const void* g, void* l) {
  __builtin_amdgcn_global_load_lds((__attribute__((address_space(1))) void*)g,
                                   (__attribute__((address_space(3))) void*)l,
                                   16, 0, 0);
}
DEV float exp2_fast(float x) {
#if __has_builtin(__builtin_amdgcn_exp2f)
  return __builtin_amdgcn_exp2f(x);
#else
  return __expf(x * 0.69314718056f);
#endif
}
template <int CTRL>
DEV float dppf(float x) {
  return __int_as_float(__builtin_amdgcn_update_dpp(0, __float_as_int(x), CTRL, 0xf, 0xf, true));
}
DEV float rowmax16(float x) {
  x = fmaxf(x, dppf<0xB1>(x));
  x = fmaxf(x, dppf<0x4E>(x));
  x = fmaxf(x, dppf<0x141>(x));
  x = fmaxf(x, dppf<0x140>(x));
  return x;
}
DEV float rowsum16(float x) {
  x += dppf<0xB1>(x);
  x += dppf<0x4E>(x);
  x += dppf<0x141>(x);
  x += dppf<0x140>(x);
  return x;
}

// ---------------- conversion kernels ----------------

__global__ __launch_bounds__(256) void cvt_bf16_k(const float* __restrict__ in,
                                                  unsigned short* __restrict__ out,
                                                  int n8) {
  int i = blockIdx.x * 256 + threadIdx.x;
  if (i >= n8) return;
  const float4* p = (const float4*)(in + (size_t)i * 8);
  float4 a = p[0], b = p[1];
  u16x8 u;
  u[0] = f2bf(a.x); u[1] = f2bf(a.y); u[2] = f2bf(a.z); u[3] = f2bf(a.w);
  u[4] = f2bf(b.x); u[5] = f2bf(b.y); u[6] = f2bf(b.z); u[7] = f2bf(b.w);
  *(u16x8*)(out + (size_t)i * 8) = u;
}

__global__ __launch_bounds__(256) void transpose_cvt(const float* __restrict__ W,
                                                     unsigned short* __restrict__ WT,
                                                     int K, int N) {
  __shared__ float tile[64][65];
  const int t = threadIdx.x;
  const int n0 = blockIdx.x * 64, k0 = blockIdx.y * 64;
#pragma unroll
  for (int rep = 0; rep < 4; ++rep) {
    int idx = rep * 256 + t;
    int r = idx >> 4, c4 = (idx & 15) * 4;
    float4 v = *(const float4*)&W[(size_t)(k0 + r) * N + n0 + c4];
    tile[r][c4] = v.x; tile[r][c4 + 1] = v.y; tile[r][c4 + 2] = v.z; tile[r][c4 + 3] = v.w;
  }
  __syncthreads();
#pragma unroll
  for (int rep = 0; rep < 2; ++rep) {
    int idx = rep * 256 + t;
    int j = idx >> 3, i0 = (idx & 7) * 8;
    u16x8 u;
#pragma unroll
    for (int i = 0; i < 8; i++) u[i] = f2bf(tile[i0 + i][j]);
    *(u16x8*)&WT[(size_t)(n0 + j) * K + k0 + i0] = u;
  }
}

// ---------------- 128x128 GEMM core, 2-buffer prefetch-before-compute ------
// (the measured ~760 TF-effective structure from round-4's out_gemm)

struct StageSmem {
  unsigned short A[128 * 64];
  unsigned short B[128 * 64];
};

DEV void stage_tile(const char* A, const char* B, StageSmem* s, int kt, int tid) {
  const int row_s = tid >> 3;
  const int kbp = (tid & 7) * 16;
#pragma unroll
  for (int st = 0; st < 4; ++st) {
    int row = st * 32 + row_s;
    int kb = kbp ^ ((row & 7) << 4);
    gload16(A + (size_t)row * (DIMC * 2) + kt * 128 + kb, (char*)s->A + st * 4096 + tid * 16);
    gload16(B + (size_t)row * (DIMC * 2) + kt * 128 + kb, (char*)s->B + st * 4096 + tid * 16);
  }
}

DEV void gemm_core(const unsigned short* __restrict__ Ap,
                   const unsigned short* __restrict__ Bp,
                   StageSmem (&sm)[2], int tid, f32x4 (&acc)[4][4]) {
  const int wave = tid >> 6, lane = tid & 63;
  const int wr = wave >> 1, wc = wave & 1;
  const int lh = lane >> 4, ll = lane & 15;

  stage_tile((const char*)Ap, (const char*)Bp, &sm[0], 0, tid);
  __syncthreads();

  for (int kt = 0; kt < 48; ++kt) {
    if (kt + 1 < 48)  // issue prefetch BEFORE compute: full K-step of cover
      stage_tile((const char*)Ap, (const char*)Bp, &sm[(kt + 1) & 1], kt + 1, tid);
    const StageSmem* s = &sm[kt & 1];
#pragma unroll
    for (int ks = 0; ks < 2; ++ks) {
      s16x8 a[4], b[4];
#pragma unroll
      for (int f = 0; f < 4; ++f) {
        int ar = wr * 64 + f * 16 + ll;
        a[f] = *(const s16x8*)((const char*)s->A + ar * 128 +
                               ((ks * 64 + lh * 16) ^ ((ar & 7) << 4)));
        int br = wc * 64 + f * 16 + ll;
        b[f] = *(const s16x8*)((const char*)s->B + br * 128 +
                               ((ks * 64 + lh * 16) ^ ((br & 7) << 4)));
      }
#pragma unroll
      for (int i = 0; i < 4; i++)
#pragma unroll
        for (int j = 0; j < 4; j++)
          acc[i][j] = __builtin_amdgcn_mfma_f32_16x16x32_bf16(a[i], b[j], acc[i][j], 0, 0, 0);
    }
    __syncthreads();  // drains prefetch (covered by MFMA above) + swaps
  }
}

// ---------------- QKV GEMM + bias + RMSnorm + RoPE epilogue ----------------

union QkvSmem {
  StageSmem st[2];
  unsigned short ctile[128 * 136];  // [128 rows][128 cols], pad to 136
};

__global__ __launch_bounds__(256, 2) void qkv_gemm(
    const unsigned short* __restrict__ X0, const unsigned short* __restrict__ X1,
    const unsigned short* __restrict__ W0, const unsigned short* __restrict__ W1,
    const float* __restrict__ b0, const float* __restrict__ b1,
    const float* __restrict__ wqa, const float* __restrict__ wka,
    const float* __restrict__ wqb, const float* __restrict__ wkb,
    const float* __restrict__ freqs,
    unsigned short* __restrict__ Qb, unsigned short* __restrict__ Kb,
    unsigned short* __restrict__ Vt, int nt0) {
  __shared__ QkvSmem sm;
  const int tid = threadIdx.x;

  // bijective XCD swizzle (1440 % 8 == 0), chunk = 180
  const int chunk = gridDim.x >> 3;
  const int nid = ((int)blockIdx.x & 7) * chunk + ((int)blockIdx.x >> 3);
  const int strm = (nid >= nt0) ? 1 : 0;
  const int t = strm ? nid - nt0 : nid;
  const int m0 = (t / 72) * 128, n0 = (t % 72) * 128;
  const unsigned short* Xp = (strm ? X1 : X0) + (size_t)m0 * DIMC;
  const unsigned short* Wp = (strm ? W1 : W0) + (size_t)n0 * DIMC;
  const float* biasp = (strm ? b1 : b0);
  const int s_off = strm ? 0 : 512;

  f32x4 acc[4][4] = {};
  gemm_core(Xp, Wp, sm.st, tid, acc);

  {  // acc + bias -> ctile (bf16)
    const int wave = tid >> 6, lane = tid & 63;
    const int wr = wave >> 1, wc = wave & 1, lh = lane >> 4, ll = lane & 15;
#pragma unroll
    for (int fn = 0; fn < 4; ++fn) {
      int c = wc * 64 + fn * 16 + ll;
      float bv = biasp[n0 + c];
#pragma unroll
      for (int fm = 0; fm < 4; ++fm)
#pragma unroll
        for (int j = 0; j < 4; j++) {
          int r = wr * 64 + fm * 16 + lh * 4 + j;
          sm.ctile[r * 136 + c] = f2bf(acc[fm][fn][j] + bv);
        }
    }
  }
  __syncthreads();

  const int qkv_idx = (t % 72) / 24;  // 24 n-tiles per {q,k,v}
  const int head = (t % 72) % 24;

  if (qkv_idx == 2) {
    // V: transposed store Vt[h][d][s]
    const int sg0 = s_off + m0;
#pragma unroll
    for (int half = 0; half < 2; ++half) {
      int d = half * 64 + (tid >> 2);
      int t0 = (tid & 3) * 32;
      size_t obase = (size_t)(head * 128 + d) * S_TOT + sg0 + t0;
#pragma unroll
      for (int v = 0; v < 4; ++v) {
        u16x8 u;
#pragma unroll
        for (int i = 0; i < 8; i++) u[i] = sm.ctile[(t0 + v * 8 + i) * 136 + d];
        *(u16x8*)&Vt[obase + v * 8] = u;
      }
    }
  } else {
    // Q/K: RMS norm over 128 cols + RoPE, store [h][s][d]
    const float* wn = (qkv_idx == 0) ? (strm ? wqb : wqa) : (strm ? wkb : wka);
    unsigned short* Ob = (qkv_idx == 0) ? Qb : Kb;
    const int row = tid >> 1, half = tid & 1;
    const int sg = s_off + m0 + row;
    float x[64];
    float ss = 0.f;
#pragma unroll
    for (int i = 0; i < 64; i++) {
      float v = bf2f(sm.ctile[row * 136 + half * 64 + i]);
      x[i] = v; ss += v * v;
    }
    ss += __shfl_xor(ss, 1);
    const float rn = rsqrtf(ss * (1.f / 128.f) + 1e-6f);
    const float* fr = freqs + (size_t)sg * 256 + half * 128;
    unsigned short o[64];
#pragma unroll
    for (int p = 0; p < 32; ++p) {
      float w0 = wn[half * 64 + 2 * p], w1 = wn[half * 64 + 2 * p + 1];
      float y0 = x[2 * p] * rn * w0, y1 = x[2 * p + 1] * rn * w1;
      float f00 = fr[p * 4], f01 = fr[p * 4 + 1], f10 = fr[p * 4 + 2], f11 = fr[p * 4 + 3];
      o[2 * p] = f2bf(f00 * y0 + f01 * y1);
      o[2 * p + 1] = f2bf(f10 * y0 + f11 * y1);
    }
    size_t ob = ((size_t)head * S_TOT + sg) * 128 + half * 64;
#pragma unroll
    for (int v = 0; v < 8; ++v) {
      u16x8 u;
#pragma unroll
      for (int i = 0; i < 8; i++) u[i] = o[v * 8 + i];
      *(u16x8*)&Ob[ob + v * 8] = u;
    }
  }
}

// ---------------- out projection (both streams, one launch) ----------------

__global__ __launch_bounds__(256, 2) void out_gemm(
    const unsigned short* __restrict__ A0, const unsigned short* __restrict__ A1,
    const unsigned short* __restrict__ W0, const unsigned short* __restrict__ W1,
    const float* __restrict__ b0, const float* __restrict__ b1,
    float* __restrict__ C0, float* __restrict__ C1, int nt0) {
  __shared__ StageSmem sm[2];
  const int tid = threadIdx.x;
  const int chunk = gridDim.x >> 3;  // 480 % 8 == 0
  const int nid = ((int)blockIdx.x & 7) * chunk + ((int)blockIdx.x >> 3);
  const int strm = (nid >= nt0) ? 1 : 0;
  const int t = strm ? nid - nt0 : nid;
  const int m0 = (t / 24) * 128, n0 = (t % 24) * 128;
  const unsigned short* Ap = (strm ? A1 : A0) + (size_t)m0 * DIMC;
  const unsigned short* Wp = (strm ? W1 : W0) + (size_t)n0 * DIMC;
  const float* bias = strm ? b1 : b0;
  float* C = strm ? C1 : C0;

  f32x4 acc[4][4] = {};
  gemm_core(Ap, Wp, sm, tid, acc);
  const int wave = tid >> 6, lane = tid & 63;
  const int wr = wave >> 1, wc = wave & 1, lh = lane >> 4, ll = lane & 15;
#pragma unroll
  for (int fn = 0; fn < 4; ++fn) {
    int c = n0 + wc * 64 + fn * 16 + ll;
    float bv = bias[c];
#pragma unroll
    for (int fm = 0; fm < 4; ++fm)
#pragma unroll
      for (int j = 0; j < 4; j++) {
        int r = m0 + wr * 64 + fm * 16 + lh * 4 + j;
        C[(size_t)r * DIMC + c] = acc[fm][fn][j] + bv;
      }
  }
}

// ---------------- flash attention (unchanged) ----------------

__global__ __launch_bounds__(256, 2) void attn_k(
    const unsigned short* __restrict__ Qb, const unsigned short* __restrict__ Kb,
    const unsigned short* __restrict__ Vt, unsigned short* __restrict__ AO) {
  __shared__ alignas(128) unsigned short Ks[2][64 * 128];
  __shared__ alignas(128) unsigned short Vs[128 * 64];
  __shared__ alignas(128) unsigned short Ps[4][32 * 72];
  __shared__ float tabA[4][32];
  __shared__ float tabL[4][32];

  const int tid = threadIdx.x, w = tid >> 6, lane = tid & 63;
  const int lh = lane >> 4, ll16 = lane & 15;
  const int ll31 = lane & 31, hi = lane >> 5;
  const int wgid = blockIdx.x;
  const int nid = (wgid & 7) * 60 + (wgid >> 3);
  const int h = nid / 20, qt = nid % 20;
  const float C = 0.12751744f;  // (1/sqrt(128)) * log2(e)

  s16x8 qf[2][4];
#pragma unroll
  for (int rb = 0; rb < 2; rb++) {
    size_t qbase = ((size_t)h * S_TOT + qt * 128 + w * 32 + rb * 16 + ll16) * 128;
#pragma unroll
    for (int ks = 0; ks < 4; ks++) qf[rb][ks] = *(const s16x8*)&Qb[qbase + ks * 32 + lh * 8];
  }

  float m2[2][4], l_r[2][4];
  f32x16 o[4] = {};
#pragma unroll
  for (int rb = 0; rb < 2; rb++)
#pragma unroll
    for (int j = 0; j < 4; j++) { m2[rb][j] = -1e30f; l_r[rb][j] = 0.f; }

  const unsigned short* Kh = Kb + (size_t)h * S_TOT * 128;
  const unsigned short* Vh = Vt + (size_t)h * 128 * S_TOT;
  unsigned short* Pw = &Ps[w][0];

  {
#pragma unroll
    for (int st = 0; st < 4; ++st) {
      int row = st * 16 + (tid >> 4);
      int col = ((tid & 15) * 16) ^ ((row & 7) << 4);
      gload16((const char*)(Kh + (size_t)row * 128) + col,
              (char*)&Ks[0][0] + st * 4096 + tid * 16);
    }
  }

  int cur = 0;
  for (int kt = 0; kt < 40; ++kt) {
    __syncthreads();
    {
      const int k0 = kt * 64;
#pragma unroll
      for (int st = 0; st < 4; ++st) {
        int row = st * 32 + (tid >> 3);
        int col = ((tid & 7) * 16) ^ ((row & 7) << 4);
        gload16((const char*)(Vh + (size_t)row * S_TOT + k0) + col,
                (char*)Vs + st * 4096 + tid * 16);
      }
    }
    if (kt + 1 < 40) {
      const unsigned short* Kn = Kh + (size_t)(kt + 1) * 64 * 128;
#pragma unroll
      for (int st = 0; st < 4; ++st) {
        int row = st * 16 + (tid >> 4);
        int col = ((tid & 15) * 16) ^ ((row & 7) << 4);
        gload16((const char*)(Kn + (size_t)row * 128) + col,
                (char*)&Ks[cur ^ 1][0] + st * 4096 + tid * 16);
      }
    }

    const char* Kc = (const char*)&Ks[cur][0];
    f32x4 sc[2][4] = {};
#pragma unroll
    for (int kb = 0; kb < 4; kb++) {
      int krow = kb * 16 + ll16;
      const char* kr = Kc + krow * 256;
      int swz = (krow & 7) << 4;
#pragma unroll
      for (int ks = 0; ks < 4; ks++) {
        s16x8 bf = *(const s16x8*)(kr + ((ks * 64 + lh * 16) ^ swz));
        sc[0][kb] = __builtin_amdgcn_mfma_f32_16x16x32_bf16(qf[0][ks], bf, sc[0][kb], 0, 0, 0);
        sc[1][kb] = __builtin_amdgcn_mfma_f32_16x16x32_bf16(qf[1][ks], bf, sc[1][kb], 0, 0, 0);
      }
    }

    float pmax[2][4];
#pragma unroll
    for (int rb = 0; rb < 2; rb++)
#pragma unroll
      for (int j = 0; j < 4; j++) {
        float v = fmaxf(fmaxf(sc[rb][0][j], sc[rb][1][j]), fmaxf(sc[rb][2][j], sc[rb][3][j]));
        pmax[rb][j] = rowmax16(v) * C;
      }
    bool need = false;
#pragma unroll
    for (int rb = 0; rb < 2; rb++)
#pragma unroll
      for (int j = 0; j < 4; j++) need |= (pmax[rb][j] > m2[rb][j] + 8.0f);
    if (__any(need)) {
#pragma unroll
      for (int rb = 0; rb < 2; rb++)
#pragma unroll
        for (int j = 0; j < 4; j++) {
          float mn = fmaxf(m2[rb][j], pmax[rb][j]);
          float al = exp2_fast(m2[rb][j] - mn);
          m2[rb][j] = mn;
          l_r[rb][j] *= al;
          if (ll16 == 0) tabA[w][rb * 16 + lh * 4 + j] = al;
        }
#pragma unroll
      for (int reg = 0; reg < 16; reg++) {
        int cr = (reg & 3) + 8 * (reg >> 2) + 4 * hi;
        float alv = tabA[w][cr];
        o[0][reg] *= alv; o[1][reg] *= alv; o[2][reg] *= alv; o[3][reg] *= alv;
      }
    }
#pragma unroll
    for (int rb = 0; rb < 2; rb++) {
      float ps0 = 0.f, ps1 = 0.f, ps2 = 0.f, ps3 = 0.f;
#pragma unroll
      for (int kb = 0; kb < 4; kb++) {
        float p0 = exp2_fast(sc[rb][kb][0] * C - m2[rb][0]);
        float p1 = exp2_fast(sc[rb][kb][1] * C - m2[rb][1]);
        float p2 = exp2_fast(sc[rb][kb][2] * C - m2[rb][2]);
        float p3 = exp2_fast(sc[rb][kb][3] * C - m2[rb][3]);
        ps0 += p0; ps1 += p1; ps2 += p2; ps3 += p3;
        int rbase = (rb * 16 + lh * 4);
        Pw[(rbase + 0) * 72 + kb * 16 + ll16] = f2bf(p0);
        Pw[(rbase + 1) * 72 + kb * 16 + ll16] = f2bf(p1);
        Pw[(rbase + 2) * 72 + kb * 16 + ll16] = f2bf(p2);
        Pw[(rbase + 3) * 72 + kb * 16 + ll16] = f2bf(p3);
      }
      l_r[rb][0] += rowsum16(ps0);
      l_r[rb][1] += rowsum16(ps1);
      l_r[rb][2] += rowsum16(ps2);
      l_r[rb][3] += rowsum16(ps3);
    }

    __syncthreads();

#pragma unroll
    for (int kstep = 0; kstep < 4; kstep++) {
      s16x8 pa = *(const s16x8*)((const char*)Pw + ll31 * 144 + kstep * 32 + hi * 16);
#pragma unroll
      for (int dblk = 0; dblk < 4; dblk++) {
        int vrow = dblk * 32 + ll31;
        s16x8 vb = *(const s16x8*)((const char*)Vs + vrow * 128 +
                                   ((kstep * 32 + hi * 16) ^ ((vrow & 7) << 4)));
        o[dblk] = __builtin_amdgcn_mfma_f32_32x32x16_bf16(pa, vb, o[dblk], 0, 0, 0);
      }
    }
    cur ^= 1;
  }

  if (ll16 == 0) {
#pragma unroll
    for (int rb = 0; rb < 2; rb++)
#pragma unroll
      for (int j = 0; j < 4; j++) tabL[w][rb * 16 + lh * 4 + j] = l_r[rb][j];
  }
#pragma unroll
  for (int reg = 0; reg < 16; reg++) {
    int cr = (reg & 3) + 8 * (reg >> 2) + 4 * hi;
    float inv = 1.0f / tabL[w][cr];
    int srow = qt * 128 + w * 32 + cr;
    size_t base = (size_t)srow * DIMC + h * 128;
#pragma unroll
    for (int dblk = 0; dblk < 4; dblk++)
      AO[base + dblk * 32 + ll31] = f2bf(o[dblk][reg] * inv);
  }
}

// ---------------- launcher ----------------

extern "C" void kernel_launch(void* const* d_in, const int* in_sizes, int n_in,
                              void* d_out, int out_size, void* d_ws, size_t ws_size,
                              hipStream_t stream) {
  (void)in_sizes; (void)n_in; (void)out_size; (void)ws_size;
  const float* Xa = (const float*)d_in[0];
  const float* Xb = (const float*)d_in[1];
  const float* freqs = (const float*)d_in[2];
  const float* Wqkv_a = (const float*)d_in[3];
  const float* bqkv_a = (const float*)d_in[4];
  const float* Wqkv_b = (const float*)d_in[5];
  const float* bqkv_b = (const float*)d_in[6];
  const float* wq_a = (const float*)d_in[7];
  const float* wk_a = (const float*)d_in[8];
  const float* wq_b = (const float*)d_in[9];
  const float* wk_b = (const float*)d_in[10];
  const float* Wout_a = (const float*)d_in[11];
  const float* bout_a = (const float*)d_in[12];
  const float* Wout_b = (const float*)d_in[13];
  const float* bout_b = (const float*)d_in[14];
  float* out = (float*)d_out;

  char* ws = (char*)d_ws;
  unsigned short* WTa  = (unsigned short*)ws; ws += (size_t)NQKV * DIMC * 2;
  unsigned short* WTb  = (unsigned short*)ws; ws += (size_t)NQKV * DIMC * 2;
  unsigned short* WoTa = (unsigned short*)ws; ws += (size_t)DIMC * DIMC * 2;
  unsigned short* WoTb = (unsigned short*)ws; ws += (size_t)DIMC * DIMC * 2;
  unsigned short* Xa16 = (unsigned short*)ws; ws += (size_t)2048 * DIMC * 2;
  unsigned short* Xb16 = (unsigned short*)ws; ws += (size_t)512 * DIMC * 2;
  unsigned short* Qb   = (unsigned short*)ws; ws += (size_t)24 * S_TOT * 128 * 2;
  unsigned short* Kbf  = (unsigned short*)ws; ws += (size_t)24 * S_TOT * 128 * 2;
  unsigned short* Vt   = (unsigned short*)ws; ws += (size_t)24 * S_TOT * 128 * 2;
  unsigned short* AO   = (unsigned short*)ws; ws += (size_t)S_TOT * DIMC * 2;

  cvt_bf16_k<<<dim3(2048 * DIMC / 8 / 256), dim3(256), 0, stream>>>(Xa, Xa16, 2048 * DIMC / 8);
  cvt_bf16_k<<<dim3(512 * DIMC / 8 / 256), dim3(256), 0, stream>>>(Xb, Xb16, 512 * DIMC / 8);
  transpose_cvt<<<dim3(NQKV / 64, DIMC / 64), dim3(256), 0, stream>>>(Wqkv_a, WTa, DIMC, NQKV);
  transpose_cvt<<<dim3(NQKV / 64, DIMC / 64), dim3(256), 0, stream>>>(Wqkv_b, WTb, DIMC, NQKV);
  transpose_cvt<<<dim3(DIMC / 64, DIMC / 64), dim3(256), 0, stream>>>(Wout_a, WoTa, DIMC, DIMC);
  transpose_cvt<<<dim3(DIMC / 64, DIMC / 64), dim3(256), 0, stream>>>(Wout_b, WoTb, DIMC, DIMC);

  // merged QKV: stream a = 16x72 tiles (1152), stream b = 4x72 (288) -> 1440
  qkv_gemm<<<dim3(1440), dim3(256), 0, stream>>>(Xa16, Xb16, WTa, WTb, bqkv_a, bqkv_b,
                                                 wq_a, wk_a, wq_b, wk_b, freqs,
                                                 Qb, Kbf, Vt, 1152);

  attn_k<<<dim3(480), dim3(256), 0, stream>>>(Qb, Kbf, Vt, AO);

  // merged out-proj: stream a = 16x24 (384), stream b = 4x24 (96) -> 480
  out_gemm<<<dim3(480), dim3(256), 0, stream>>>(AO + (size_t)512 * DIMC, AO, WoTa, WoTb,
                                                bout_a, bout_b, out,
                                                out + (size_t)2048 * DIMC, 384);
}

// Round 7
// 482.053 us; speedup vs baseline: 1.3593x; 1.0107x over previous
//
#include <hip/hip_runtime.h>
#include <hip/hip_bf16.h>

// FluxJointAttention on MI355X (gfx950), bf16 MFMA pipeline.
// Round 7: tile-order locality fix. qkv/out GEMM tiles mapped in 4x4
// supergroups (16 tiles share 4 A-panels + 4 B-panels ~ 6.3 MB) nested in
// bijective XCD chunks -> L2-miss fill volume (the measured 2.77 TB/s
// serializer, FETCH 574 MB) drops ~2-3x. Core/pipeline/epilogues unchanged.

typedef __attribute__((ext_vector_type(8))) short s16x8;
typedef __attribute__((ext_vector_type(8))) unsigned short u16x8;
typedef __attribute__((ext_vector_type(4))) float f32x4;
typedef __attribute__((ext_vector_type(16))) float f32x16;

#define DEV static __device__ __forceinline__

#define S_TOT 2560
#define DIMC 3072
#define NQKV 9216

DEV unsigned short f2bf(float f) {
  union { float f; unsigned u; } v; v.f = f;
  return (unsigned short)((v.u + 0x7fffu + ((v.u >> 16) & 1u)) >> 16);
}
DEV float bf2f(unsigned short h) {
  union { unsigned u; float f; } v; v.u = ((unsigned)h) << 16;
  return v.f;
}
DEV void gload16(const void* g, void* l) {
  __builtin_amdgcn_global_load_lds((__attribute__((address_space(1))) void*)g,
                                   (__attribute__((address_space(3))) void*)l,
                                   16, 0, 0);
}
DEV float exp2_fast(float x) {
#if __has_builtin(__builtin_amdgcn_exp2f)
  return __builtin_amdgcn_exp2f(x);
#else
  return __expf(x * 0.69314718056f);
#endif
}
template <int CTRL>
DEV float dppf(float x) {
  return __int_as_float(__builtin_amdgcn_update_dpp(0, __float_as_int(x), CTRL, 0xf, 0xf, true));
}
DEV float rowmax16(float x) {
  x = fmaxf(x, dppf<0xB1>(x));
  x = fmaxf(x, dppf<0x4E>(x));
  x = fmaxf(x, dppf<0x141>(x));
  x = fmaxf(x, dppf<0x140>(x));
  return x;
}
DEV float rowsum16(float x) {
  x += dppf<0xB1>(x);
  x += dppf<0x4E>(x);
  x += dppf<0x141>(x);
  x += dppf<0x140>(x);
  return x;
}

// 4x4 supergroup tile map: 16 consecutive ids cover a 4m x 4n square.
// mgrid must be a multiple of 4 (or exactly 4 -> mgs=1).
DEV void tile_map(int t, int mgrid, int* m, int* n) {
  int sg = t >> 4, loc = t & 15;
  int mgs = mgrid >> 2;
  int mg = sg % mgs, ng = sg / mgs;
  *m = mg * 4 + (loc & 3);
  *n = ng * 4 + (loc >> 2);
}

// ---------------- conversion kernels ----------------

__global__ __launch_bounds__(256) void cvt_bf16_k(const float* __restrict__ in,
                                                  unsigned short* __restrict__ out,
                                                  int n8) {
  int i = blockIdx.x * 256 + threadIdx.x;
  if (i >= n8) return;
  const float4* p = (const float4*)(in + (size_t)i * 8);
  float4 a = p[0], b = p[1];
  u16x8 u;
  u[0] = f2bf(a.x); u[1] = f2bf(a.y); u[2] = f2bf(a.z); u[3] = f2bf(a.w);
  u[4] = f2bf(b.x); u[5] = f2bf(b.y); u[6] = f2bf(b.z); u[7] = f2bf(b.w);
  *(u16x8*)(out + (size_t)i * 8) = u;
}

__global__ __launch_bounds__(256) void transpose_cvt(const float* __restrict__ W,
                                                     unsigned short* __restrict__ WT,
                                                     int K, int N) {
  __shared__ float tile[64][65];
  const int t = threadIdx.x;
  const int n0 = blockIdx.x * 64, k0 = blockIdx.y * 64;
#pragma unroll
  for (int rep = 0; rep < 4; ++rep) {
    int idx = rep * 256 + t;
    int r = idx >> 4, c4 = (idx & 15) * 4;
    float4 v = *(const float4*)&W[(size_t)(k0 + r) * N + n0 + c4];
    tile[r][c4] = v.x; tile[r][c4 + 1] = v.y; tile[r][c4 + 2] = v.z; tile[r][c4 + 3] = v.w;
  }
  __syncthreads();
#pragma unroll
  for (int rep = 0; rep < 2; ++rep) {
    int idx = rep * 256 + t;
    int j = idx >> 3, i0 = (idx & 7) * 8;
    u16x8 u;
#pragma unroll
    for (int i = 0; i < 8; i++) u[i] = f2bf(tile[i0 + i][j]);
    *(u16x8*)&WT[(size_t)(n0 + j) * K + k0 + i0] = u;
  }
}

// ---------------- 128x128 GEMM core, 2-buffer prefetch-before-compute ------

struct StageSmem {
  unsigned short A[128 * 64];
  unsigned short B[128 * 64];
};

DEV void stage_tile(const char* A, const char* B, StageSmem* s, int kt, int tid) {
  const int row_s = tid >> 3;
  const int kbp = (tid & 7) * 16;
#pragma unroll
  for (int st = 0; st < 4; ++st) {
    int row = st * 32 + row_s;
    int kb = kbp ^ ((row & 7) << 4);
    gload16(A + (size_t)row * (DIMC * 2) + kt * 128 + kb, (char*)s->A + st * 4096 + tid * 16);
    gload16(B + (size_t)row * (DIMC * 2) + kt * 128 + kb, (char*)s->B + st * 4096 + tid * 16);
  }
}

DEV void gemm_core(const unsigned short* __restrict__ Ap,
                   const unsigned short* __restrict__ Bp,
                   StageSmem (&sm)[2], int tid, f32x4 (&acc)[4][4]) {
  const int wave = tid >> 6, lane = tid & 63;
  const int wr = wave >> 1, wc = wave & 1;
  const int lh = lane >> 4, ll = lane & 15;

  stage_tile((const char*)Ap, (const char*)Bp, &sm[0], 0, tid);
  __syncthreads();

  for (int kt = 0; kt < 48; ++kt) {
    if (kt + 1 < 48)  // issue prefetch BEFORE compute: full K-step of cover
      stage_tile((const char*)Ap, (const char*)Bp, &sm[(kt + 1) & 1], kt + 1, tid);
    const StageSmem* s = &sm[kt & 1];
#pragma unroll
    for (int ks = 0; ks < 2; ++ks) {
      s16x8 a[4], b[4];
#pragma unroll
      for (int f = 0; f < 4; ++f) {
        int ar = wr * 64 + f * 16 + ll;
        a[f] = *(const s16x8*)((const char*)s->A + ar * 128 +
                               ((ks * 64 + lh * 16) ^ ((ar & 7) << 4)));
        int br = wc * 64 + f * 16 + ll;
        b[f] = *(const s16x8*)((const char*)s->B + br * 128 +
                               ((ks * 64 + lh * 16) ^ ((br & 7) << 4)));
      }
#pragma unroll
      for (int i = 0; i < 4; i++)
#pragma unroll
        for (int j = 0; j < 4; j++)
          acc[i][j] = __builtin_amdgcn_mfma_f32_16x16x32_bf16(a[i], b[j], acc[i][j], 0, 0, 0);
    }
    __syncthreads();  // drains prefetch (covered by MFMA above) + swaps
  }
}

// ---------------- QKV GEMM + bias + RMSnorm + RoPE epilogue ----------------

union QkvSmem {
  StageSmem st[2];
  unsigned short ctile[128 * 136];  // [128 rows][128 cols], pad to 136
};

__global__ __launch_bounds__(256, 2) void qkv_gemm(
    const unsigned short* __restrict__ X0, const unsigned short* __restrict__ X1,
    const unsigned short* __restrict__ W0, const unsigned short* __restrict__ W1,
    const float* __restrict__ b0, const float* __restrict__ b1,
    const float* __restrict__ wqa, const float* __restrict__ wka,
    const float* __restrict__ wqb, const float* __restrict__ wkb,
    const float* __restrict__ freqs,
    unsigned short* __restrict__ Qb, unsigned short* __restrict__ Kb,
    unsigned short* __restrict__ Vt, int nt0) {
  __shared__ QkvSmem sm;
  const int tid = threadIdx.x;

  // bijective XCD swizzle (1440 % 8 == 0), chunk = 180
  const int chunk = gridDim.x >> 3;
  const int nid = ((int)blockIdx.x & 7) * chunk + ((int)blockIdx.x >> 3);
  const int strm = (nid >= nt0) ? 1 : 0;
  const int t = strm ? nid - nt0 : nid;
  int mt, nt;
  tile_map(t, strm ? 4 : 16, &mt, &nt);   // 4x4 supergroup L2 locality
  const int m0 = mt * 128, n0 = nt * 128;
  const unsigned short* Xp = (strm ? X1 : X0) + (size_t)m0 * DIMC;
  const unsigned short* Wp = (strm ? W1 : W0) + (size_t)n0 * DIMC;
  const float* biasp = (strm ? b1 : b0);
  const int s_off = strm ? 0 : 512;

  f32x4 acc[4][4] = {};
  gemm_core(Xp, Wp, sm.st, tid, acc);

  {  // acc + bias -> ctile (bf16)
    const int wave = tid >> 6, lane = tid & 63;
    const int wr = wave >> 1, wc = wave & 1, lh = lane >> 4, ll = lane & 15;
#pragma unroll
    for (int fn = 0; fn < 4; ++fn) {
      int c = wc * 64 + fn * 16 + ll;
      float bv = biasp[n0 + c];
#pragma unroll
      for (int fm = 0; fm < 4; ++fm)
#pragma unroll
        for (int j = 0; j < 4; j++) {
          int r = wr * 64 + fm * 16 + lh * 4 + j;
          sm.ctile[r * 136 + c] = f2bf(acc[fm][fn][j] + bv);
        }
    }
  }
  __syncthreads();

  const int qkv_idx = nt / 24;  // 24 n-tiles per {q,k,v}
  const int head = nt % 24;

  if (qkv_idx == 2) {
    // V: transposed store Vt[h][d][s]
    const int sg0 = s_off + m0;
#pragma unroll
    for (int half = 0; half < 2; ++half) {
      int d = half * 64 + (tid >> 2);
      int t0 = (tid & 3) * 32;
      size_t obase = (size_t)(head * 128 + d) * S_TOT + sg0 + t0;
#pragma unroll
      for (int v = 0; v < 4; ++v) {
        u16x8 u;
#pragma unroll
        for (int i = 0; i < 8; i++) u[i] = sm.ctile[(t0 + v * 8 + i) * 136 + d];
        *(u16x8*)&Vt[obase + v * 8] = u;
      }
    }
  } else {
    // Q/K: RMS norm over 128 cols + RoPE, store [h][s][d]
    const float* wn = (qkv_idx == 0) ? (strm ? wqb : wqa) : (strm ? wkb : wka);
    unsigned short* Ob = (qkv_idx == 0) ? Qb : Kb;
    const int row = tid >> 1, half = tid & 1;
    const int sg = s_off + m0 + row;
    float x[64];
    float ss = 0.f;
#pragma unroll
    for (int i = 0; i < 64; i++) {
      float v = bf2f(sm.ctile[row * 136 + half * 64 + i]);
      x[i] = v; ss += v * v;
    }
    ss += __shfl_xor(ss, 1);
    const float rn = rsqrtf(ss * (1.f / 128.f) + 1e-6f);
    const float* fr = freqs + (size_t)sg * 256 + half * 128;
    unsigned short o[64];
#pragma unroll
    for (int p = 0; p < 32; ++p) {
      float w0 = wn[half * 64 + 2 * p], w1 = wn[half * 64 + 2 * p + 1];
      float y0 = x[2 * p] * rn * w0, y1 = x[2 * p + 1] * rn * w1;
      float f00 = fr[p * 4], f01 = fr[p * 4 + 1], f10 = fr[p * 4 + 2], f11 = fr[p * 4 + 3];
      o[2 * p] = f2bf(f00 * y0 + f01 * y1);
      o[2 * p + 1] = f2bf(f10 * y0 + f11 * y1);
    }
    size_t ob = ((size_t)head * S_TOT + sg) * 128 + half * 64;
#pragma unroll
    for (int v = 0; v < 8; ++v) {
      u16x8 u;
#pragma unroll
      for (int i = 0; i < 8; i++) u[i] = o[v * 8 + i];
      *(u16x8*)&Ob[ob + v * 8] = u;
    }
  }
}

// ---------------- out projection (both streams, one launch) ----------------

__global__ __launch_bounds__(256, 2) void out_gemm(
    const unsigned short* __restrict__ A0, const unsigned short* __restrict__ A1,
    const unsigned short* __restrict__ W0, const unsigned short* __restrict__ W1,
    const float* __restrict__ b0, const float* __restrict__ b1,
    float* __restrict__ C0, float* __restrict__ C1, int nt0) {
  __shared__ StageSmem sm[2];
  const int tid = threadIdx.x;
  const int chunk = gridDim.x >> 3;  // 480 % 8 == 0
  const int nid = ((int)blockIdx.x & 7) * chunk + ((int)blockIdx.x >> 3);
  const int strm = (nid >= nt0) ? 1 : 0;
  const int t = strm ? nid - nt0 : nid;
  int mt, nt;
  tile_map(t, strm ? 4 : 16, &mt, &nt);
  const int m0 = mt * 128, n0 = nt * 128;
  const unsigned short* Ap = (strm ? A1 : A0) + (size_t)m0 * DIMC;
  const unsigned short* Wp = (strm ? W1 : W0) + (size_t)n0 * DIMC;
  const float* bias = strm ? b1 : b0;
  float* C = strm ? C1 : C0;

  f32x4 acc[4][4] = {};
  gemm_core(Ap, Wp, sm, tid, acc);
  const int wave = tid >> 6, lane = tid & 63;
  const int wr = wave >> 1, wc = wave & 1, lh = lane >> 4, ll = lane & 15;
#pragma unroll
  for (int fn = 0; fn < 4; ++fn) {
    int c = n0 + wc * 64 + fn * 16 + ll;
    float bv = bias[c];
#pragma unroll
    for (int fm = 0; fm < 4; ++fm)
#pragma unroll
      for (int j = 0; j < 4; j++) {
        int r = m0 + wr * 64 + fm * 16 + lh * 4 + j;
        C[(size_t)r * DIMC + c] = acc[fm][fn][j] + bv;
      }
  }
}

// ---------------- flash attention (unchanged) ----------------

__global__ __launch_bounds__(256, 2) void attn_k(
    const unsigned short* __restrict__ Qb, const unsigned short* __restrict__ Kb,
    const unsigned short* __restrict__ Vt, unsigned short* __restrict__ AO) {
  __shared__ alignas(128) unsigned short Ks[2][64 * 128];
  __shared__ alignas(128) unsigned short Vs[128 * 64];
  __shared__ alignas(128) unsigned short Ps[4][32 * 72];
  __shared__ float tabA[4][32];
  __shared__ float tabL[4][32];

  const int tid = threadIdx.x, w = tid >> 6, lane = tid & 63;
  const int lh = lane >> 4, ll16 = lane & 15;
  const int ll31 = lane & 31, hi = lane >> 5;
  const int wgid = blockIdx.x;
  const int nid = (wgid & 7) * 60 + (wgid >> 3);
  const int h = nid / 20, qt = nid % 20;
  const float C = 0.12751744f;  // (1/sqrt(128)) * log2(e)

  s16x8 qf[2][4];
#pragma unroll
  for (int rb = 0; rb < 2; rb++) {
    size_t qbase = ((size_t)h * S_TOT + qt * 128 + w * 32 + rb * 16 + ll16) * 128;
#pragma unroll
    for (int ks = 0; ks < 4; ks++) qf[rb][ks] = *(const s16x8*)&Qb[qbase + ks * 32 + lh * 8];
  }

  float m2[2][4], l_r[2][4];
  f32x16 o[4] = {};
#pragma unroll
  for (int rb = 0; rb < 2; rb++)
#pragma unroll
    for (int j = 0; j < 4; j++) { m2[rb][j] = -1e30f; l_r[rb][j] = 0.f; }

  const unsigned short* Kh = Kb + (size_t)h * S_TOT * 128;
  const unsigned short* Vh = Vt + (size_t)h * 128 * S_TOT;
  unsigned short* Pw = &Ps[w][0];

  {
#pragma unroll
    for (int st = 0; st < 4; ++st) {
      int row = st * 16 + (tid >> 4);
      int col = ((tid & 15) * 16) ^ ((row & 7) << 4);
      gload16((const char*)(Kh + (size_t)row * 128) + col,
              (char*)&Ks[0][0] + st * 4096 + tid * 16);
    }
  }

  int cur = 0;
  for (int kt = 0; kt < 40; ++kt) {
    __syncthreads();
    {
      const int k0 = kt * 64;
#pragma unroll
      for (int st = 0; st < 4; ++st) {
        int row = st * 32 + (tid >> 3);
        int col = ((tid & 7) * 16) ^ ((row & 7) << 4);
        gload16((const char*)(Vh + (size_t)row * S_TOT + k0) + col,
                (char*)Vs + st * 4096 + tid * 16);
      }
    }
    if (kt + 1 < 40) {
      const unsigned short* Kn = Kh + (size_t)(kt + 1) * 64 * 128;
#pragma unroll
      for (int st = 0; st < 4; ++st) {
        int row = st * 16 + (tid >> 4);
        int col = ((tid & 15) * 16) ^ ((row & 7) << 4);
        gload16((const char*)(Kn + (size_t)row * 128) + col,
                (char*)&Ks[cur ^ 1][0] + st * 4096 + tid * 16);
      }
    }

    const char* Kc = (const char*)&Ks[cur][0];
    f32x4 sc[2][4] = {};
#pragma unroll
    for (int kb = 0; kb < 4; kb++) {
      int krow = kb * 16 + ll16;
      const char* kr = Kc + krow * 256;
      int swz = (krow & 7) << 4;
#pragma unroll
      for (int ks = 0; ks < 4; ks++) {
        s16x8 bf = *(const s16x8*)(kr + ((ks * 64 + lh * 16) ^ swz));
        sc[0][kb] = __builtin_amdgcn_mfma_f32_16x16x32_bf16(qf[0][ks], bf, sc[0][kb], 0, 0, 0);
        sc[1][kb] = __builtin_amdgcn_mfma_f32_16x16x32_bf16(qf[1][ks], bf, sc[1][kb], 0, 0, 0);
      }
    }

    float pmax[2][4];
#pragma unroll
    for (int rb = 0; rb < 2; rb++)
#pragma unroll
      for (int j = 0; j < 4; j++) {
        float v = fmaxf(fmaxf(sc[rb][0][j], sc[rb][1][j]), fmaxf(sc[rb][2][j], sc[rb][3][j]));
        pmax[rb][j] = rowmax16(v) * C;
      }
    bool need = false;
#pragma unroll
    for (int rb = 0; rb < 2; rb++)
#pragma unroll
      for (int j = 0; j < 4; j++) need |= (pmax[rb][j] > m2[rb][j] + 8.0f);
    if (__any(need)) {
#pragma unroll
      for (int rb = 0; rb < 2; rb++)
#pragma unroll
        for (int j = 0; j < 4; j++) {
          float mn = fmaxf(m2[rb][j], pmax[rb][j]);
          float al = exp2_fast(m2[rb][j] - mn);
          m2[rb][j] = mn;
          l_r[rb][j] *= al;
          if (ll16 == 0) tabA[w][rb * 16 + lh * 4 + j] = al;
        }
#pragma unroll
      for (int reg = 0; reg < 16; reg++) {
        int cr = (reg & 3) + 8 * (reg >> 2) + 4 * hi;
        float alv = tabA[w][cr];
        o[0][reg] *= alv; o[1][reg] *= alv; o[2][reg] *= alv; o[3][reg] *= alv;
      }
    }
#pragma unroll
    for (int rb = 0; rb < 2; rb++) {
      float ps0 = 0.f, ps1 = 0.f, ps2 = 0.f, ps3 = 0.f;
#pragma unroll
      for (int kb = 0; kb < 4; kb++) {
        float p0 = exp2_fast(sc[rb][kb][0] * C - m2[rb][0]);
        float p1 = exp2_fast(sc[rb][kb][1] * C - m2[rb][1]);
        float p2 = exp2_fast(sc[rb][kb][2] * C - m2[rb][2]);
        float p3 = exp2_fast(sc[rb][kb][3] * C - m2[rb][3]);
        ps0 += p0; ps1 += p1; ps2 += p2; ps3 += p3;
        int rbase = (rb * 16 + lh * 4);
        Pw[(rbase + 0) * 72 + kb * 16 + ll16] = f2bf(p0);
        Pw[(rbase + 1) * 72 + kb * 16 + ll16] = f2bf(p1);
        Pw[(rbase + 2) * 72 + kb * 16 + ll16] = f2bf(p2);
        Pw[(rbase + 3) * 72 + kb * 16 + ll16] = f2bf(p3);
      }
      l_r[rb][0] += rowsum16(ps0);
      l_r[rb][1] += rowsum16(ps1);
      l_r[rb][2] += rowsum16(ps2);
      l_r[rb][3] += rowsum16(ps3);
    }

    __syncthreads();

#pragma unroll
    for (int kstep = 0; kstep < 4; kstep++) {
      s16x8 pa = *(const s16x8*)((const char*)Pw + ll31 * 144 + kstep * 32 + hi * 16);
#pragma unroll
      for (int dblk = 0; dblk < 4; dblk++) {
        int vrow = dblk * 32 + ll31;
        s16x8 vb = *(const s16x8*)((const char*)Vs + vrow * 128 +
                                   ((kstep * 32 + hi * 16) ^ ((vrow & 7) << 4)));
        o[dblk] = __builtin_amdgcn_mfma_f32_32x32x16_bf16(pa, vb, o[dblk], 0, 0, 0);
      }
    }
    cur ^= 1;
  }

  if (ll16 == 0) {
#pragma unroll
    for (int rb = 0; rb < 2; rb++)
#pragma unroll
      for (int j = 0; j < 4; j++) tabL[w][rb * 16 + lh * 4 + j] = l_r[rb][j];
  }
#pragma unroll
  for (int reg = 0; reg < 16; reg++) {
    int cr = (reg & 3) + 8 * (reg >> 2) + 4 * hi;
    float inv = 1.0f / tabL[w][cr];
    int srow = qt * 128 + w * 32 + cr;
    size_t base = (size_t)srow * DIMC + h * 128;
#pragma unroll
    for (int dblk = 0; dblk < 4; dblk++)
      AO[base + dblk * 32 + ll31] = f2bf(o[dblk][reg] * inv);
  }
}

// ---------------- launcher ----------------

extern "C" void kernel_launch(void* const* d_in, const int* in_sizes, int n_in,
                              void* d_out, int out_size, void* d_ws, size_t ws_size,
                              hipStream_t stream) {
  (void)in_sizes; (void)n_in; (void)out_size; (void)ws_size;
  const float* Xa = (const float*)d_in[0];
  const float* Xb = (const float*)d_in[1];
  const float* freqs = (const float*)d_in[2];
  const float* Wqkv_a = (const float*)d_in[3];
  const float* bqkv_a = (const float*)d_in[4];
  const float* Wqkv_b = (const float*)d_in[5];
  const float* bqkv_b = (const float*)d_in[6];
  const float* wq_a = (const float*)d_in[7];
  const float* wk_a = (const float*)d_in[8];
  const float* wq_b = (const float*)d_in[9];
  const float* wk_b = (const float*)d_in[10];
  const float* Wout_a = (const float*)d_in[11];
  const float* bout_a = (const float*)d_in[12];
  const float* Wout_b = (const float*)d_in[13];
  const float* bout_b = (const float*)d_in[14];
  float* out = (float*)d_out;

  char* ws = (char*)d_ws;
  unsigned short* WTa  = (unsigned short*)ws; ws += (size_t)NQKV * DIMC * 2;
  unsigned short* WTb  = (unsigned short*)ws; ws += (size_t)NQKV * DIMC * 2;
  unsigned short* WoTa = (unsigned short*)ws; ws += (size_t)DIMC * DIMC * 2;
  unsigned short* WoTb = (unsigned short*)ws; ws += (size_t)DIMC * DIMC * 2;
  unsigned short* Xa16 = (unsigned short*)ws; ws += (size_t)2048 * DIMC * 2;
  unsigned short* Xb16 = (unsigned short*)ws; ws += (size_t)512 * DIMC * 2;
  unsigned short* Qb   = (unsigned short*)ws; ws += (size_t)24 * S_TOT * 128 * 2;
  unsigned short* Kbf  = (unsigned short*)ws; ws += (size_t)24 * S_TOT * 128 * 2;
  unsigned short* Vt   = (unsigned short*)ws; ws += (size_t)24 * S_TOT * 128 * 2;
  unsigned short* AO   = (unsigned short*)ws; ws += (size_t)S_TOT * DIMC * 2;

  cvt_bf16_k<<<dim3(2048 * DIMC / 8 / 256), dim3(256), 0, stream>>>(Xa, Xa16, 2048 * DIMC / 8);
  cvt_bf16_k<<<dim3(512 * DIMC / 8 / 256), dim3(256), 0, stream>>>(Xb, Xb16, 512 * DIMC / 8);
  transpose_cvt<<<dim3(NQKV / 64, DIMC / 64), dim3(256), 0, stream>>>(Wqkv_a, WTa, DIMC, NQKV);
  transpose_cvt<<<dim3(NQKV / 64, DIMC / 64), dim3(256), 0, stream>>>(Wqkv_b, WTb, DIMC, NQKV);
  transpose_cvt<<<dim3(DIMC / 64, DIMC / 64), dim3(256), 0, stream>>>(Wout_a, WoTa, DIMC, DIMC);
  transpose_cvt<<<dim3(DIMC / 64, DIMC / 64), dim3(256), 0, stream>>>(Wout_b, WoTb, DIMC, DIMC);

  // merged QKV: stream a = 16x72 tiles (1152), stream b = 4x72 (288) -> 1440
  qkv_gemm<<<dim3(1440), dim3(256), 0, stream>>>(Xa16, Xb16, WTa, WTb, bqkv_a, bqkv_b,
                                                 wq_a, wk_a, wq_b, wk_b, freqs,
                                                 Qb, Kbf, Vt, 1152);

  attn_k<<<dim3(480), dim3(256), 0, stream>>>(Qb, Kbf, Vt, AO);

  // merged out-proj: stream a = 16x24 (384), stream b = 4x24 (96) -> 480
  out_gemm<<<dim3(480), dim3(256), 0, stream>>>(AO + (size_t)512 * DIMC, AO, WoTa, WoTb,
                                                bout_a, bout_b, out,
                                                out + (size_t)2048 * DIMC, 384);
}